// Round 7
// baseline (483.942 us; speedup 1.0000x reference)
//
#include <hip/hip_runtime.h>
#include <hip/hip_fp16.h>
#include <math.h>

#define NNODES 100000
#define NEDGES 1600000
#define DIM 128
#define NG 64
#define GATE 512
#define CH 16
#define SCAN_NB 98  // ceil(NNODES / 1024)
#define FILL_NPASS 4
#define BUCKET ((NNODES + FILL_NPASS - 1) / FILL_NPASS)  // 25000

struct alignas(8) half4v { __half2 a, b; };

// fast sigmoid/tanh: v_exp_f32 + v_rcp_f32 (absmax headroom is ~100x)
__device__ __forceinline__ float sigf(float x) {
    return __builtin_amdgcn_rcpf(1.0f + __expf(-x));
}
__device__ __forceinline__ float tanhfast(float x) {
    float e = __expf(2.0f * x);
    return 1.0f - 2.0f * __builtin_amdgcn_rcpf(e + 1.0f);
}
__device__ __forceinline__ float4 h4tof4(half4v v) {
    float2 p = __half22float2(v.a);
    float2 q = __half22float2(v.b);
    return make_float4(p.x, p.y, q.x, q.y);
}

// in-degree count by col (int atomics)
__global__ __launch_bounds__(256) void k_deg(const int* __restrict__ ei, int* __restrict__ deg) {
    int e = blockIdx.x * 256 + threadIdx.x;
    if (e < NEDGES) atomicAdd(&deg[ei[NEDGES + e]], 1);
}

// stage 1: per-block exclusive scan of deg; block sums out
__global__ __launch_bounds__(1024) void k_scan1(const int* __restrict__ deg, int* __restrict__ row_ptr,
                                                int* __restrict__ bsum) {
    __shared__ int ls[1024];
    int tid = threadIdx.x;
    int n = blockIdx.x * 1024 + tid;
    int v = (n < NNODES) ? deg[n] : 0;
    ls[tid] = v;
    __syncthreads();
    for (int off = 1; off < 1024; off <<= 1) {
        int t = (tid >= off) ? ls[tid - off] : 0;
        __syncthreads();
        ls[tid] += t;
        __syncthreads();
    }
    if (n < NNODES) row_ptr[n] = ls[tid] - v;  // exclusive within block
    if (tid == 1023) bsum[blockIdx.x] = ls[1023];
}

// stage 2: exclusive scan of block sums + graph segment bounds (batch sorted)
__global__ __launch_bounds__(128) void k_scan2(int* __restrict__ bsum, int* __restrict__ row_ptr,
                                               const int* __restrict__ batch, int* __restrict__ start) {
    __shared__ int ls[128];
    int tid = threadIdx.x;
    int v = (tid < SCAN_NB) ? bsum[tid] : 0;
    ls[tid] = v;
    __syncthreads();
    for (int off = 1; off < 128; off <<= 1) {
        int t = (tid >= off) ? ls[tid - off] : 0;
        __syncthreads();
        ls[tid] += t;
        __syncthreads();
    }
    if (tid < SCAN_NB) bsum[tid] = ls[tid] - v;  // exclusive block offsets
    if (tid == 127) row_ptr[NNODES] = ls[127];
    // graph bounds via binary search
    if (tid <= NG) {
        int lo = 0, hi = NNODES;
        while (lo < hi) {
            int mid = (lo + hi) >> 1;
            if (batch[mid] < tid) lo = mid + 1; else hi = mid;
        }
        start[tid] = lo;
    }
}

// stage 3: add block offsets; init cursor = row_ptr; compute dinv
__global__ __launch_bounds__(1024) void k_scan3(const int* __restrict__ deg, int* __restrict__ row_ptr,
                                                const int* __restrict__ bsum, int* __restrict__ cursor,
                                                float* __restrict__ dinv) {
    int n = blockIdx.x * 1024 + threadIdx.x;
    if (n < NNODES) {
        int rp = row_ptr[n] + bsum[blockIdx.x];
        row_ptr[n] = rp;
        cursor[n] = rp;
        dinv[n] = rsqrtf((float)deg[n] + 1.0f);
    }
}

// adj[cursor[col]++] = row, only for cols in [b0, b0+BUCKET): temporal
// bucketing keeps the adj write window at 1.6 MB -> lines fill in L2
__global__ __launch_bounds__(256) void k_fillb(const int* __restrict__ ei, int* __restrict__ cursor,
                                               int* __restrict__ adj, int b0) {
    int e = blockIdx.x * 256 + threadIdx.x;
    if (e < NEDGES) {
        int col = ei[NEDGES + e];
        if (col >= b0 && col < b0 + BUCKET) {
            int row = ei[e];
            int pos = atomicAdd(&cursor[col], 1);
            adj[pos] = row;
        }
    }
}

// y[n] = (x[n] @ W) * dinv[n], stored fp16
__global__ __launch_bounds__(256) void k_gemm(const float* __restrict__ x, const float* __restrict__ W,
                                              const float* __restrict__ dinv, half4v* __restrict__ yh) {
    __shared__ float4 Wl[DIM * DIM / 4];  // 64 KB
    const float4* W4 = (const float4*)W;
    int tid = threadIdx.x;
#pragma unroll
    for (int l = 0; l < 16; ++l) Wl[tid + l * 256] = W4[tid + l * 256];
    __syncthreads();

    int tr = tid >> 5, tc = tid & 31;
    int rb = blockIdx.x * 64;
    const float4* x4 = (const float4*)x;

    int r[8];
    bool valid[8];
#pragma unroll
    for (int i = 0; i < 8; ++i) {
        int rr = rb + tr * 8 + i;
        valid[i] = rr < NNODES;
        r[i] = valid[i] ? rr : (NNODES - 1);
    }

    float4 acc[8];
#pragma unroll
    for (int i = 0; i < 8; ++i) acc[i] = make_float4(0.f, 0.f, 0.f, 0.f);

    for (int k = 0; k < DIM; k += 4) {
        float4 wv[4];
#pragma unroll
        for (int kk = 0; kk < 4; ++kk) wv[kk] = Wl[(k + kk) * 32 + tc];
#pragma unroll
        for (int i = 0; i < 8; ++i) {
            float4 xv = x4[(size_t)r[i] * 32 + (k >> 2)];
            acc[i].x += xv.x * wv[0].x + xv.y * wv[1].x + xv.z * wv[2].x + xv.w * wv[3].x;
            acc[i].y += xv.x * wv[0].y + xv.y * wv[1].y + xv.z * wv[2].y + xv.w * wv[3].y;
            acc[i].z += xv.x * wv[0].z + xv.y * wv[1].z + xv.z * wv[2].z + xv.w * wv[3].z;
            acc[i].w += xv.x * wv[0].w + xv.y * wv[1].w + xv.z * wv[2].w + xv.w * wv[3].w;
        }
    }

#pragma unroll
    for (int i = 0; i < 8; ++i) {
        if (valid[i]) {
            float dv = dinv[r[i]];
            half4v v;
            v.a = __floats2half2_rn(acc[i].x * dv, acc[i].y * dv);
            v.b = __floats2half2_rn(acc[i].z * dv, acc[i].w * dv);
            yh[(size_t)r[i] * 32 + tc] = v;
        }
    }
}

// agg2[n] = y[n] + sum over in-neighbors y[row]  (CSR gather, fp16 in/out, f32 accum)
__global__ __launch_bounds__(256) void k_gather(const int* __restrict__ row_ptr, const int* __restrict__ adj,
                                                const half4v* __restrict__ yh, half4v* __restrict__ agg2) {
    int grp = threadIdx.x >> 5;  // 8 nodes per block
    int l = threadIdx.x & 31;    // 32 lanes x 4 dims = 128 dims
    int n = blockIdx.x * 8 + grp;
    if (n >= NNODES) return;
    int s = row_ptr[n], e = row_ptr[n + 1];
    float4 a0 = h4tof4(yh[(size_t)n * 32 + l]);  // self-loop term
    float4 a1 = make_float4(0.f, 0.f, 0.f, 0.f);
    int i = s;
    for (; i + 1 < e; i += 2) {
        int r0 = adj[i], r1 = adj[i + 1];
        float4 v0 = h4tof4(yh[(size_t)r0 * 32 + l]);
        float4 v1 = h4tof4(yh[(size_t)r1 * 32 + l]);
        a0.x += v0.x; a0.y += v0.y; a0.z += v0.z; a0.w += v0.w;
        a1.x += v1.x; a1.y += v1.y; a1.z += v1.z; a1.w += v1.w;
    }
    if (i < e) {
        float4 v0 = h4tof4(yh[(size_t)adj[i] * 32 + l]);
        a0.x += v0.x; a0.y += v0.y; a0.z += v0.z; a0.w += v0.w;
    }
    half4v o;
    o.a = __floats2half2_rn(a0.x + a1.x, a0.y + a1.y);
    o.b = __floats2half2_rn(a0.z + a1.z, a0.w + a1.w);
    agg2[(size_t)n * 32 + l] = o;
}

// sums[g][d] = sum over nodes of relu(dinv[n]*agg2[n][d] + b[d])
__global__ __launch_bounds__(128) void k_pool(const __half* __restrict__ agg2, const float* __restrict__ dinv,
                                              const float* __restrict__ b, const int* __restrict__ start,
                                              float* __restrict__ sums) {
    int g = blockIdx.x / CH, q = blockIdx.x % CH;
    int d = threadIdx.x;
    int s = start[g], e = start[g + 1];
    int len = e - s;
    int n0 = s + (int)((long)len * q / CH);
    int n1 = s + (int)((long)len * (q + 1) / CH);
    float bias = b[d];
    float acc = 0.f;
    for (int n = n0; n < n1; ++n) {
        float v = dinv[n] * __half2float(agg2[(size_t)n * DIM + d]) + bias;
        acc += fmaxf(v, 0.f);
    }
    atomicAdd(&sums[g * DIM + d], acc);
}

// xg[t][j] = b_ih[j] + b_hh[j] + pooled[t] . w_ih[j]
__global__ __launch_bounds__(512) void k_xgate(const float* __restrict__ sums, const int* __restrict__ start,
                                               const float* __restrict__ w_ih, const float* __restrict__ b_ih,
                                               const float* __restrict__ b_hh, float* __restrict__ xg) {
    __shared__ float4 p4[DIM / 4];
    int t = blockIdx.x, j = threadIdx.x;
    if (j < DIM) {
        int c = start[t + 1] - start[t];
        float inv = 1.0f / fmaxf((float)c, 1.0f);
        ((float*)p4)[j] = sums[t * DIM + j] * inv;
    }
    __syncthreads();
    const float4* w4 = (const float4*)(w_ih + (size_t)j * DIM);
    float acc = b_ih[j] + b_hh[j];
#pragma unroll
    for (int kk = 0; kk < 32; ++kk) {
        float4 w = w4[kk];
        float4 p = p4[kk];
        acc += w.x * p.x + w.y * p.y + w.z * p.z + w.w * p.w;
    }
    xg[t * GATE + j] = acc;
}

// sequential LSTM recurrence + final FC, single block of 512 (8 waves).
// __launch_bounds__(512, 2): 2 waves/EU -> VGPR cap 256, so the 128-VGPR
// weight array STAYS in registers (R6 pathology: cap 128 -> compiler
// re-loaded w_hh from L2 every step = ~2500 cy/step). The empty asm
// "+v" touch pins each loaded value as a register def the compiler
// cannot rematerialize as a global load inside the t-loop.
__global__ __launch_bounds__(512, 2) void k_lstm(const float* __restrict__ xg, const float* __restrict__ w_hh,
                                                 const float* __restrict__ Wfc, const float* __restrict__ bfc,
                                                 float* __restrict__ out) {
    __shared__ float h_lds[DIM];
    __shared__ float gates[GATE];
    __shared__ float hs[NG * DIM];  // 32 KB
    int j = threadIdx.x;

    // w_hh row j in registers (128 VGPRs), pinned
    float4 wv[32];
    const float4* w4 = (const float4*)(w_hh + (size_t)j * DIM);
#pragma unroll
    for (int kk = 0; kk < 32; ++kk) {
        wv[kk] = w4[kk];
        asm volatile("" : "+v"(wv[kk].x), "+v"(wv[kk].y), "+v"(wv[kk].z), "+v"(wv[kk].w));
    }

    float c = 0.f;
    if (j < DIM) h_lds[j] = 0.f;
    float xcur = xg[j];  // t=0 pre-activation
    __syncthreads();

    const float4* h4 = (const float4*)h_lds;
    for (int t = 0; t < NG; ++t) {
        // prefetch next step's xg early; result needed only next iteration
        float xnext = (t + 1 < NG) ? xg[(t + 1) * GATE + j] : 0.f;
        float a0 = xcur, a1 = 0.f, a2 = 0.f, a3 = 0.f;
#pragma unroll
        for (int kk = 0; kk < 32; ++kk) {
            float4 hv = h4[kk];  // lane-uniform -> LDS broadcast
            float4 w = wv[kk];
            a0 += w.x * hv.x;
            a1 += w.y * hv.y;
            a2 += w.z * hv.z;
            a3 += w.w * hv.w;
        }
        gates[j] = (a0 + a1) + (a2 + a3);
        __syncthreads();
        if (j < DIM) {
            float gi = gates[j], gf = gates[DIM + j], gg = gates[2 * DIM + j], go = gates[3 * DIM + j];
            c = sigf(gf) * c + sigf(gi) * tanhfast(gg);
            float hn = sigf(go) * tanhfast(c);
            h_lds[j] = hn;
            hs[t * DIM + j] = hn;
        }
        xcur = xnext;
        __syncthreads();
    }

    // FC: out[t][cls] = b_fc[cls] + hs[t] . W_fc[cls]
    for (int o = j; o < NG * 10; o += 512) {
        int t = o / 10, cls = o - t * 10;
        const float4* hv4 = (const float4*)(hs + t * DIM);
        const float4* wf4 = (const float4*)(Wfc + cls * DIM);
        float acc = bfc[cls];
#pragma unroll
        for (int kk = 0; kk < 32; ++kk) {
            float4 h = hv4[kk];
            float4 w = wf4[kk];
            acc += h.x * w.x + h.y * w.y + h.z * w.z + h.w * w.w;
        }
        out[o] = acc;
    }
}

extern "C" void kernel_launch(void* const* d_in, const int* in_sizes, int n_in,
                              void* d_out, int out_size, void* d_ws, size_t ws_size,
                              hipStream_t stream) {
    const float* x     = (const float*)d_in[0];
    const int*   ei    = (const int*)d_in[1];
    const int*   batch = (const int*)d_in[2];
    const float* W_gcn = (const float*)d_in[3];
    const float* b_gcn = (const float*)d_in[4];
    const float* w_ih  = (const float*)d_in[5];
    const float* w_hh  = (const float*)d_in[6];
    const float* b_ih  = (const float*)d_in[7];
    const float* b_hh  = (const float*)d_in[8];
    const float* W_fc  = (const float*)d_in[9];
    const float* b_fc  = (const float*)d_in[10];
    float* out = (float*)d_out;

    char* ws = (char*)d_ws;
    half4v* yh    = (half4v*)ws;                                   // 25.6 MB
    half4v* agg2  = (half4v*)(ws + (size_t)NNODES * DIM * 2);      // 25.6 MB
    float*  dinv  = (float*)(ws + (size_t)NNODES * DIM * 4);       // 400 KB
    float*  sums  = dinv + 100096;
    float*  xg    = sums + NG * DIM;
    int*    deg   = (int*)(xg + NG * GATE);
    int*    row_ptr = deg + 100096;
    int*    cursor  = row_ptr + 100096;
    int*    adj     = cursor + 100096;      // 6.4 MB
    int*    start   = adj + NEDGES;
    int*    bsum    = start + 128;

    hipMemsetAsync(deg, 0, NNODES * sizeof(int), stream);
    hipMemsetAsync(sums, 0, NG * DIM * sizeof(float), stream);

    k_deg<<<(NEDGES + 255) / 256, 256, 0, stream>>>(ei, deg);
    k_scan1<<<SCAN_NB, 1024, 0, stream>>>(deg, row_ptr, bsum);
    k_scan2<<<1, 128, 0, stream>>>(bsum, row_ptr, batch, start);
    k_scan3<<<SCAN_NB, 1024, 0, stream>>>(deg, row_ptr, bsum, cursor, dinv);
    for (int p = 0; p < FILL_NPASS; ++p)
        k_fillb<<<(NEDGES + 255) / 256, 256, 0, stream>>>(ei, cursor, adj, p * BUCKET);
    k_gemm<<<(NNODES + 63) / 64, 256, 0, stream>>>(x, W_gcn, dinv, yh);
    k_gather<<<(NNODES + 7) / 8, 256, 0, stream>>>(row_ptr, adj, yh, agg2);
    k_pool<<<NG * CH, 128, 0, stream>>>((const __half*)agg2, dinv, b_gcn, start, sums);
    k_xgate<<<NG, 512, 0, stream>>>(sums, start, w_ih, b_ih, b_hh, xg);
    k_lstm<<<1, 512, 0, stream>>>(xg, w_hh, W_fc, b_fc, out);
}

// Round 8
// 458.244 us; speedup vs baseline: 1.0561x; 1.0561x over previous
//
#include <hip/hip_runtime.h>
#include <hip/hip_fp16.h>
#include <math.h>

#define NNODES 100000
#define NEDGES 1600000
#define DIM 128
#define NG 64
#define GATE 512
#define CH 16
#define SCAN_NB 98  // ceil(NNODES / 1024)
#define FILL_NPASS 4
#define BUCKET ((NNODES + FILL_NPASS - 1) / FILL_NPASS)  // 25000

// k_lstm2 dynamic LDS layout
#define SMEM_W   131072                       // 64 pairs x 512 rows x 4B (fp16 pairs)
#define SMEM_AUX (256 + 2048 + 16384)         // h2h + gates + hsh
#define SMEM_TOTAL (SMEM_W + SMEM_AUX)        // 149760 <= 160K/CU

struct alignas(8) half4v { __half2 a, b; };
typedef _Float16 f16x2 __attribute__((ext_vector_type(2)));

__device__ __forceinline__ f16x2 f2h2cast(float f) {
    union U { float f; f16x2 h; } u; u.f = f; return u.h;
}
__device__ __forceinline__ float fdot2f(f16x2 a, f16x2 b, float c) {
#if __has_builtin(__builtin_amdgcn_fdot2)
    return __builtin_amdgcn_fdot2(a, b, c, false);
#else
    return c + (float)a[0] * (float)b[0] + (float)a[1] * (float)b[1];
#endif
}

// fast sigmoid/tanh: v_exp_f32 + v_rcp_f32 (absmax headroom is ~100x)
__device__ __forceinline__ float sigf(float x) {
    return __builtin_amdgcn_rcpf(1.0f + __expf(-x));
}
__device__ __forceinline__ float tanhfast(float x) {
    float e = __expf(2.0f * x);
    return 1.0f - 2.0f * __builtin_amdgcn_rcpf(e + 1.0f);
}
__device__ __forceinline__ float4 h4tof4(half4v v) {
    float2 p = __half22float2(v.a);
    float2 q = __half22float2(v.b);
    return make_float4(p.x, p.y, q.x, q.y);
}

// in-degree count by col (int atomics)
__global__ __launch_bounds__(256) void k_deg(const int* __restrict__ ei, int* __restrict__ deg) {
    int e = blockIdx.x * 256 + threadIdx.x;
    if (e < NEDGES) atomicAdd(&deg[ei[NEDGES + e]], 1);
}

// stage 1: per-block exclusive scan of deg; block sums out
__global__ __launch_bounds__(1024) void k_scan1(const int* __restrict__ deg, int* __restrict__ row_ptr,
                                                int* __restrict__ bsum) {
    __shared__ int ls[1024];
    int tid = threadIdx.x;
    int n = blockIdx.x * 1024 + tid;
    int v = (n < NNODES) ? deg[n] : 0;
    ls[tid] = v;
    __syncthreads();
    for (int off = 1; off < 1024; off <<= 1) {
        int t = (tid >= off) ? ls[tid - off] : 0;
        __syncthreads();
        ls[tid] += t;
        __syncthreads();
    }
    if (n < NNODES) row_ptr[n] = ls[tid] - v;  // exclusive within block
    if (tid == 1023) bsum[blockIdx.x] = ls[1023];
}

// stage 2: exclusive scan of block sums + graph segment bounds (batch sorted)
__global__ __launch_bounds__(128) void k_scan2(int* __restrict__ bsum, int* __restrict__ row_ptr,
                                               const int* __restrict__ batch, int* __restrict__ start) {
    __shared__ int ls[128];
    int tid = threadIdx.x;
    int v = (tid < SCAN_NB) ? bsum[tid] : 0;
    ls[tid] = v;
    __syncthreads();
    for (int off = 1; off < 128; off <<= 1) {
        int t = (tid >= off) ? ls[tid - off] : 0;
        __syncthreads();
        ls[tid] += t;
        __syncthreads();
    }
    if (tid < SCAN_NB) bsum[tid] = ls[tid] - v;  // exclusive block offsets
    if (tid == 127) row_ptr[NNODES] = ls[127];
    // graph bounds via binary search
    if (tid <= NG) {
        int lo = 0, hi = NNODES;
        while (lo < hi) {
            int mid = (lo + hi) >> 1;
            if (batch[mid] < tid) lo = mid + 1; else hi = mid;
        }
        start[tid] = lo;
    }
}

// stage 3: add block offsets; init cursor = row_ptr; compute dinv
__global__ __launch_bounds__(1024) void k_scan3(const int* __restrict__ deg, int* __restrict__ row_ptr,
                                                const int* __restrict__ bsum, int* __restrict__ cursor,
                                                float* __restrict__ dinv) {
    int n = blockIdx.x * 1024 + threadIdx.x;
    if (n < NNODES) {
        int rp = row_ptr[n] + bsum[blockIdx.x];
        row_ptr[n] = rp;
        cursor[n] = rp;
        dinv[n] = rsqrtf((float)deg[n] + 1.0f);
    }
}

// adj[cursor[col]++] = row, only for cols in [b0, b0+BUCKET): temporal
// bucketing keeps the adj write window at 1.6 MB -> lines fill in L2
__global__ __launch_bounds__(256) void k_fillb(const int* __restrict__ ei, int* __restrict__ cursor,
                                               int* __restrict__ adj, int b0) {
    int e = blockIdx.x * 256 + threadIdx.x;
    if (e < NEDGES) {
        int col = ei[NEDGES + e];
        if (col >= b0 && col < b0 + BUCKET) {
            int row = ei[e];
            int pos = atomicAdd(&cursor[col], 1);
            adj[pos] = row;
        }
    }
}

// y[n] = (x[n] @ W) * dinv[n], stored fp16
__global__ __launch_bounds__(256) void k_gemm(const float* __restrict__ x, const float* __restrict__ W,
                                              const float* __restrict__ dinv, half4v* __restrict__ yh) {
    __shared__ float4 Wl[DIM * DIM / 4];  // 64 KB
    const float4* W4 = (const float4*)W;
    int tid = threadIdx.x;
#pragma unroll
    for (int l = 0; l < 16; ++l) Wl[tid + l * 256] = W4[tid + l * 256];
    __syncthreads();

    int tr = tid >> 5, tc = tid & 31;
    int rb = blockIdx.x * 64;
    const float4* x4 = (const float4*)x;

    int r[8];
    bool valid[8];
#pragma unroll
    for (int i = 0; i < 8; ++i) {
        int rr = rb + tr * 8 + i;
        valid[i] = rr < NNODES;
        r[i] = valid[i] ? rr : (NNODES - 1);
    }

    float4 acc[8];
#pragma unroll
    for (int i = 0; i < 8; ++i) acc[i] = make_float4(0.f, 0.f, 0.f, 0.f);

    for (int k = 0; k < DIM; k += 4) {
        float4 wv[4];
#pragma unroll
        for (int kk = 0; kk < 4; ++kk) wv[kk] = Wl[(k + kk) * 32 + tc];
#pragma unroll
        for (int i = 0; i < 8; ++i) {
            float4 xv = x4[(size_t)r[i] * 32 + (k >> 2)];
            acc[i].x += xv.x * wv[0].x + xv.y * wv[1].x + xv.z * wv[2].x + xv.w * wv[3].x;
            acc[i].y += xv.x * wv[0].y + xv.y * wv[1].y + xv.z * wv[2].y + xv.w * wv[3].y;
            acc[i].z += xv.x * wv[0].z + xv.y * wv[1].z + xv.z * wv[2].z + xv.w * wv[3].z;
            acc[i].w += xv.x * wv[0].w + xv.y * wv[1].w + xv.z * wv[2].w + xv.w * wv[3].w;
        }
    }

#pragma unroll
    for (int i = 0; i < 8; ++i) {
        if (valid[i]) {
            float dv = dinv[r[i]];
            half4v v;
            v.a = __floats2half2_rn(acc[i].x * dv, acc[i].y * dv);
            v.b = __floats2half2_rn(acc[i].z * dv, acc[i].w * dv);
            yh[(size_t)r[i] * 32 + tc] = v;
        }
    }
}

// agg2[n] = y[n] + sum over in-neighbors y[row]  (CSR gather, fp16 in/out, f32 accum)
__global__ __launch_bounds__(256) void k_gather(const int* __restrict__ row_ptr, const int* __restrict__ adj,
                                                const half4v* __restrict__ yh, half4v* __restrict__ agg2) {
    int grp = threadIdx.x >> 5;  // 8 nodes per block
    int l = threadIdx.x & 31;    // 32 lanes x 4 dims = 128 dims
    int n = blockIdx.x * 8 + grp;
    if (n >= NNODES) return;
    int s = row_ptr[n], e = row_ptr[n + 1];
    float4 a0 = h4tof4(yh[(size_t)n * 32 + l]);  // self-loop term
    float4 a1 = make_float4(0.f, 0.f, 0.f, 0.f);
    int i = s;
    for (; i + 1 < e; i += 2) {
        int r0 = adj[i], r1 = adj[i + 1];
        float4 v0 = h4tof4(yh[(size_t)r0 * 32 + l]);
        float4 v1 = h4tof4(yh[(size_t)r1 * 32 + l]);
        a0.x += v0.x; a0.y += v0.y; a0.z += v0.z; a0.w += v0.w;
        a1.x += v1.x; a1.y += v1.y; a1.z += v1.z; a1.w += v1.w;
    }
    if (i < e) {
        float4 v0 = h4tof4(yh[(size_t)adj[i] * 32 + l]);
        a0.x += v0.x; a0.y += v0.y; a0.z += v0.z; a0.w += v0.w;
    }
    half4v o;
    o.a = __floats2half2_rn(a0.x + a1.x, a0.y + a1.y);
    o.b = __floats2half2_rn(a0.z + a1.z, a0.w + a1.w);
    agg2[(size_t)n * 32 + l] = o;
}

// sums[g][d] = sum over nodes of relu(dinv[n]*agg2[n][d] + b[d])
__global__ __launch_bounds__(128) void k_pool(const __half* __restrict__ agg2, const float* __restrict__ dinv,
                                              const float* __restrict__ b, const int* __restrict__ start,
                                              float* __restrict__ sums) {
    int g = blockIdx.x / CH, q = blockIdx.x % CH;
    int d = threadIdx.x;
    int s = start[g], e = start[g + 1];
    int len = e - s;
    int n0 = s + (int)((long)len * q / CH);
    int n1 = s + (int)((long)len * (q + 1) / CH);
    float bias = b[d];
    float acc = 0.f;
    for (int n = n0; n < n1; ++n) {
        float v = dinv[n] * __half2float(agg2[(size_t)n * DIM + d]) + bias;
        acc += fmaxf(v, 0.f);
    }
    atomicAdd(&sums[g * DIM + d], acc);
}

// xg[t][j] = b_ih[j] + b_hh[j] + pooled[t] . w_ih[j]
__global__ __launch_bounds__(512) void k_xgate(const float* __restrict__ sums, const int* __restrict__ start,
                                               const float* __restrict__ w_ih, const float* __restrict__ b_ih,
                                               const float* __restrict__ b_hh, float* __restrict__ xg) {
    __shared__ float4 p4[DIM / 4];
    int t = blockIdx.x, j = threadIdx.x;
    if (j < DIM) {
        int c = start[t + 1] - start[t];
        float inv = 1.0f / fmaxf((float)c, 1.0f);
        ((float*)p4)[j] = sums[t * DIM + j] * inv;
    }
    __syncthreads();
    const float4* w4 = (const float4*)(w_ih + (size_t)j * DIM);
    float acc = b_ih[j] + b_hh[j];
#pragma unroll
    for (int kk = 0; kk < 32; ++kk) {
        float4 w = w4[kk];
        float4 p = p4[kk];
        acc += w.x * p.x + w.y * p.y + w.z * p.z + w.w * p.w;
    }
    xg[t * GATE + j] = acc;
}

// w_hh -> fp16 pair-transposed: w2g[p*512 + j] = (w_hh[j][2p], w_hh[j][2p+1])
__global__ __launch_bounds__(256) void k_wcvt(const float* __restrict__ w_hh, __half2* __restrict__ w2g) {
    int t = blockIdx.x * 256 + threadIdx.x;
    if (t < 64 * GATE) {
        int p = t >> 9, j = t & 511;
        w2g[t] = __floats2half2_rn(w_hh[(size_t)j * DIM + 2 * p], w_hh[(size_t)j * DIM + 2 * p + 1]);
    }
}

// Sequential LSTM + FC. Weights fp16, transposed pair layout.
// LDSW=1: weights resident in 128 KB LDS; ds_read_b32 at addr p*2048+j*4 is
// lane-consecutive -> conflict-free; h read via b128 broadcast (free).
// Per step: 128 KB LDS stream @ ~128 B/cy ~= 1024 cy (vs R5-R7's 256 KB/step
// L2->L1 weight reload ~= 4100 cy, which the reg allocator forced on us).
// LDSW=0 fallback (if 150 KB dynamic LDS unavailable): stream fp16 from L2.
template <int LDSW>
__global__ __launch_bounds__(512) void k_lstm2(const float* __restrict__ xg, const __half2* __restrict__ w2g,
                                               const float* __restrict__ Wfc, const float* __restrict__ bfc,
                                               float* __restrict__ out) {
    extern __shared__ char smem[];
    f16x2* w2 = (f16x2*)smem;                          // LDSW only
    char* aux = LDSW ? (smem + SMEM_W) : smem;
    __half* h2h = (__half*)aux;                        // 128 halves
    float* gates = (float*)(aux + 256);                // 512 f32
    __half* hsh = (__half*)(aux + 256 + 2048);         // 64*128 halves
    int j = threadIdx.x;

    if (LDSW) {
#pragma unroll 8
        for (int p = 0; p < 64; ++p) {
            union { __half2 h; f16x2 v; } u;
            u.h = w2g[p * GATE + j];   // coalesced read
            w2[p * GATE + j] = u.v;    // conflict-free write
        }
    }
    if (j < DIM) h2h[j] = __float2half(0.f);
    float c = 0.f;
    float xcur = xg[j];
    __syncthreads();

    const f16x2* wrow = LDSW ? (const f16x2*)w2 : (const f16x2*)w2g;
    const float4* h4 = (const float4*)h2h;
    for (int t = 0; t < NG; ++t) {
        float xnext = (t + 1 < NG) ? xg[(t + 1) * GATE + j] : 0.f;
        float acc = xcur;
#pragma unroll
        for (int pc = 0; pc < 8; ++pc) {
            float4 r0 = h4[pc * 2];      // broadcast, 8 h-pairs per chunk
            float4 r1 = h4[pc * 2 + 1];
            f16x2 hc[8];
            hc[0] = f2h2cast(r0.x); hc[1] = f2h2cast(r0.y);
            hc[2] = f2h2cast(r0.z); hc[3] = f2h2cast(r0.w);
            hc[4] = f2h2cast(r1.x); hc[5] = f2h2cast(r1.y);
            hc[6] = f2h2cast(r1.z); hc[7] = f2h2cast(r1.w);
#pragma unroll
            for (int q = 0; q < 8; ++q)
                acc = fdot2f(wrow[(pc * 8 + q) * GATE + j], hc[q], acc);
        }
        gates[j] = acc;
        __syncthreads();
        if (j < DIM) {
            float gi = gates[j], gf = gates[DIM + j], gg = gates[2 * DIM + j], go = gates[3 * DIM + j];
            c = sigf(gf) * c + sigf(gi) * tanhfast(gg);
            float hn = sigf(go) * tanhfast(c);
            h2h[j] = __float2half(hn);
            hsh[t * DIM + j] = __float2half(hn);
        }
        xcur = xnext;
        __syncthreads();
    }

    // FC: out[t][cls] = b_fc[cls] + hs[t] . W_fc[cls]
    for (int o = j; o < NG * 10; o += 512) {
        int t = o / 10, cls = o - t * 10;
        const __half2* hv = (const __half2*)(hsh + t * DIM);
        float acc = bfc[cls];
#pragma unroll
        for (int kk = 0; kk < 64; ++kk) {
            float2 hf = __half22float2(hv[kk]);
            acc += hf.x * Wfc[cls * DIM + 2 * kk] + hf.y * Wfc[cls * DIM + 2 * kk + 1];
        }
        out[o] = acc;
    }
}

extern "C" void kernel_launch(void* const* d_in, const int* in_sizes, int n_in,
                              void* d_out, int out_size, void* d_ws, size_t ws_size,
                              hipStream_t stream) {
    const float* x     = (const float*)d_in[0];
    const int*   ei    = (const int*)d_in[1];
    const int*   batch = (const int*)d_in[2];
    const float* W_gcn = (const float*)d_in[3];
    const float* b_gcn = (const float*)d_in[4];
    const float* w_ih  = (const float*)d_in[5];
    const float* w_hh  = (const float*)d_in[6];
    const float* b_ih  = (const float*)d_in[7];
    const float* b_hh  = (const float*)d_in[8];
    const float* W_fc  = (const float*)d_in[9];
    const float* b_fc  = (const float*)d_in[10];
    float* out = (float*)d_out;

    char* ws = (char*)d_ws;
    half4v* yh    = (half4v*)ws;                                   // 25.6 MB
    half4v* agg2  = (half4v*)(ws + (size_t)NNODES * DIM * 2);      // 25.6 MB
    float*  dinv  = (float*)(ws + (size_t)NNODES * DIM * 4);       // 400 KB
    float*  sums  = dinv + 100096;
    float*  xg    = sums + NG * DIM;
    int*    deg   = (int*)(xg + NG * GATE);
    int*    row_ptr = deg + 100096;
    int*    cursor  = row_ptr + 100096;
    int*    adj     = cursor + 100096;      // 6.4 MB
    int*    start   = adj + NEDGES;
    int*    bsum    = start + 128;
    __half2* w2g    = (__half2*)(bsum + 128);  // 128 KB fp16 weights

    hipMemsetAsync(deg, 0, NNODES * sizeof(int), stream);
    hipMemsetAsync(sums, 0, NG * DIM * sizeof(float), stream);

    k_deg<<<(NEDGES + 255) / 256, 256, 0, stream>>>(ei, deg);
    k_scan1<<<SCAN_NB, 1024, 0, stream>>>(deg, row_ptr, bsum);
    k_scan2<<<1, 128, 0, stream>>>(bsum, row_ptr, batch, start);
    k_scan3<<<SCAN_NB, 1024, 0, stream>>>(deg, row_ptr, bsum, cursor, dinv);
    for (int p = 0; p < FILL_NPASS; ++p)
        k_fillb<<<(NEDGES + 255) / 256, 256, 0, stream>>>(ei, cursor, adj, p * BUCKET);
    k_gemm<<<(NNODES + 63) / 64, 256, 0, stream>>>(x, W_gcn, dinv, yh);
    k_gather<<<(NNODES + 7) / 8, 256, 0, stream>>>(row_ptr, adj, yh, agg2);
    k_pool<<<NG * CH, 128, 0, stream>>>((const __half*)agg2, dinv, b_gcn, start, sums);
    k_xgate<<<NG, 512, 0, stream>>>(sums, start, w_ih, b_ih, b_hh, xg);
    k_wcvt<<<(64 * GATE + 255) / 256, 256, 0, stream>>>(w_hh, w2g);

    // Prefer LDS-resident weights (150 KB dynamic LDS); deterministic fallback.
    bool lds_ok = hipFuncSetAttribute((const void*)k_lstm2<1>,
                                      hipFuncAttributeMaxDynamicSharedMemorySize,
                                      SMEM_TOTAL) == hipSuccess;
    if (lds_ok)
        k_lstm2<1><<<1, 512, SMEM_TOTAL, stream>>>(xg, w2g, W_fc, b_fc, out);
    else
        k_lstm2<0><<<1, 512, SMEM_AUX, stream>>>(xg, w2g, W_fc, b_fc, out);
}

// Round 9
// 382.014 us; speedup vs baseline: 1.2668x; 1.1995x over previous
//
#include <hip/hip_runtime.h>
#include <hip/hip_fp16.h>
#include <math.h>

#define NNODES 100000
#define NEDGES 1600000
#define DIM 128
#define NG 64
#define GATE 512
#define SCAN_NB 98  // ceil(NNODES / 1024)
#define FILL_NPASS 4
#define BUCKET ((NNODES + FILL_NPASS - 1) / FILL_NPASS)  // 25000

// k_lstm2 dynamic LDS layout
#define SMEM_W   131072                       // 64 pairs x 512 rows x 4B (fp16 pairs)
#define SMEM_AUX (256 + 2048 + 16384)         // h2h + gates + hsh
#define SMEM_TOTAL (SMEM_W + SMEM_AUX)        // 149760 <= 160K/CU

struct alignas(8) half4v { __half2 a, b; };
typedef _Float16 f16x2 __attribute__((ext_vector_type(2)));
typedef _Float16 half8_t __attribute__((ext_vector_type(8)));
typedef float f32x4 __attribute__((ext_vector_type(4)));

__device__ __forceinline__ f16x2 f2h2cast(float f) {
    union U { float f; f16x2 h; } u; u.f = f; return u.h;
}
__device__ __forceinline__ float fdot2f(f16x2 a, f16x2 b, float c) {
#if __has_builtin(__builtin_amdgcn_fdot2)
    return __builtin_amdgcn_fdot2(a, b, c, false);
#else
    return c + (float)a[0] * (float)b[0] + (float)a[1] * (float)b[1];
#endif
}

// fast sigmoid/tanh: v_exp_f32 + v_rcp_f32 (absmax headroom is ~100x)
__device__ __forceinline__ float sigf(float x) {
    return __builtin_amdgcn_rcpf(1.0f + __expf(-x));
}
__device__ __forceinline__ float tanhfast(float x) {
    float e = __expf(2.0f * x);
    return 1.0f - 2.0f * __builtin_amdgcn_rcpf(e + 1.0f);
}

// in-degree count by col (int atomics)
__global__ __launch_bounds__(256) void k_deg(const int* __restrict__ ei, int* __restrict__ deg) {
    int e = blockIdx.x * 256 + threadIdx.x;
    if (e < NEDGES) atomicAdd(&deg[ei[NEDGES + e]], 1);
}

// stage 1: per-block exclusive scan of deg; block sums out
__global__ __launch_bounds__(1024) void k_scan1(const int* __restrict__ deg, int* __restrict__ row_ptr,
                                                int* __restrict__ bsum) {
    __shared__ int ls[1024];
    int tid = threadIdx.x;
    int n = blockIdx.x * 1024 + tid;
    int v = (n < NNODES) ? deg[n] : 0;
    ls[tid] = v;
    __syncthreads();
    for (int off = 1; off < 1024; off <<= 1) {
        int t = (tid >= off) ? ls[tid - off] : 0;
        __syncthreads();
        ls[tid] += t;
        __syncthreads();
    }
    if (n < NNODES) row_ptr[n] = ls[tid] - v;  // exclusive within block
    if (tid == 1023) bsum[blockIdx.x] = ls[1023];
}

// stage 2: exclusive scan of block sums + graph segment bounds (batch sorted)
__global__ __launch_bounds__(128) void k_scan2(int* __restrict__ bsum, int* __restrict__ row_ptr,
                                               const int* __restrict__ batch, int* __restrict__ start) {
    __shared__ int ls[128];
    int tid = threadIdx.x;
    int v = (tid < SCAN_NB) ? bsum[tid] : 0;
    ls[tid] = v;
    __syncthreads();
    for (int off = 1; off < 128; off <<= 1) {
        int t = (tid >= off) ? ls[tid - off] : 0;
        __syncthreads();
        ls[tid] += t;
        __syncthreads();
    }
    if (tid < SCAN_NB) bsum[tid] = ls[tid] - v;  // exclusive block offsets
    if (tid == 127) row_ptr[NNODES] = ls[127];
    // graph bounds via binary search
    if (tid <= NG) {
        int lo = 0, hi = NNODES;
        while (lo < hi) {
            int mid = (lo + hi) >> 1;
            if (batch[mid] < tid) lo = mid + 1; else hi = mid;
        }
        start[tid] = lo;
    }
}

// stage 3: add block offsets; init cursor = row_ptr; compute dinv
__global__ __launch_bounds__(1024) void k_scan3(const int* __restrict__ deg, int* __restrict__ row_ptr,
                                                const int* __restrict__ bsum, int* __restrict__ cursor,
                                                float* __restrict__ dinv) {
    int n = blockIdx.x * 1024 + threadIdx.x;
    if (n < NNODES) {
        int rp = row_ptr[n] + bsum[blockIdx.x];
        row_ptr[n] = rp;
        cursor[n] = rp;
        dinv[n] = rsqrtf((float)deg[n] + 1.0f);
    }
}

// adj[cursor[col]++] = row, only for cols in [b0, b0+BUCKET): temporal
// bucketing keeps the adj write window at 1.6 MB -> lines fill in L2
__global__ __launch_bounds__(256) void k_fillb(const int* __restrict__ ei, int* __restrict__ cursor,
                                               int* __restrict__ adj, int b0) {
    int e = blockIdx.x * 256 + threadIdx.x;
    if (e < NEDGES) {
        int col = ei[NEDGES + e];
        if (col >= b0 && col < b0 + BUCKET) {
            int row = ei[e];
            int pos = atomicAdd(&cursor[col], 1);
            adj[pos] = row;
        }
    }
}

// W f32 [k][d] -> Wt fp16 [d][k] (transposed, 32 KB, stays L1/L2-hot)
__global__ __launch_bounds__(256) void k_wt(const float* __restrict__ W, __half* __restrict__ Wt) {
    int t = blockIdx.x * 256 + threadIdx.x;
    if (t < DIM * DIM) {
        int d = t >> 7, k = t & 127;
        Wt[t] = __float2half(W[k * DIM + d]);
    }
}

// y[n] = (x[n] @ W) * dinv[n] via v_mfma_f32_16x16x32_f16, fp16 out.
// Block = 256 thr = 4 waves; wave wt owns rows [rb+wt*16, +16), all 128 cols.
// Frags: A lane: row=lane&15, k=(lane>>4)*8+[0..8); B lane: col=lane&15, same k;
// C: col=lane&15, row=(lane>>4)*4+reg  [m89-verified layout family].
__global__ __launch_bounds__(256) void k_gemmm(const float* __restrict__ x, const __half* __restrict__ Wt,
                                               const float* __restrict__ dinv, __half* __restrict__ yh) {
    int tid = threadIdx.x;
    int wt = tid >> 6, lane = tid & 63;
    int lr = lane & 15, kgrp = lane >> 4;
    int rb = blockIdx.x * 64 + wt * 16;

    int rowA = rb + lr;
    if (rowA >= NNODES) rowA = NNODES - 1;
    const float4* x4 = (const float4*)x;

    f32x4 acc[8];
#pragma unroll
    for (int ct = 0; ct < 8; ++ct) acc[ct] = (f32x4){0.f, 0.f, 0.f, 0.f};

#pragma unroll
    for (int c = 0; c < 4; ++c) {
        int kb = c * 32 + kgrp * 8;
        float4 v0 = x4[(size_t)rowA * 32 + (kb >> 2)];
        float4 v1 = x4[(size_t)rowA * 32 + (kb >> 2) + 1];
        half8_t a;
        a[0] = (_Float16)v0.x; a[1] = (_Float16)v0.y; a[2] = (_Float16)v0.z; a[3] = (_Float16)v0.w;
        a[4] = (_Float16)v1.x; a[5] = (_Float16)v1.y; a[6] = (_Float16)v1.z; a[7] = (_Float16)v1.w;
#pragma unroll
        for (int ct = 0; ct < 8; ++ct) {
            int col = ct * 16 + lr;
            half8_t b = *(const half8_t*)(Wt + (size_t)col * DIM + kb);
            acc[ct] = __builtin_amdgcn_mfma_f32_16x16x32_f16(a, b, acc[ct], 0, 0, 0);
        }
    }

    int rowbase = rb + kgrp * 4;
    float dv[4];
    bool ok[4];
#pragma unroll
    for (int r = 0; r < 4; ++r) {
        int row = rowbase + r;
        ok[r] = row < NNODES;
        dv[r] = ok[r] ? dinv[row] : 0.f;
    }
#pragma unroll
    for (int ct = 0; ct < 8; ++ct) {
#pragma unroll
        for (int r = 0; r < 4; ++r) {
            if (ok[r])
                yh[(size_t)(rowbase + r) * DIM + ct * 16 + lr] = __float2half(acc[ct][r] * dv[r]);
        }
    }
}

// Fused gather + ReLU + mean-pool partial sums.
// 16 lanes/node x dwordx4 (16 B = 8 dims each); 16 nodes/block (grid exact:
// 100000/16 = 6250). agg row stays in registers; relu(dinv*agg+b) block-reduced
// per graph in LDS, then ~128 atomics/block into sums. agg2 buffer eliminated.
__global__ __launch_bounds__(256) void k_gpool(const int* __restrict__ row_ptr, const int* __restrict__ adj,
                                               const float4* __restrict__ Y, const float* __restrict__ dinv,
                                               const float* __restrict__ bias, const int* __restrict__ batch,
                                               float* __restrict__ sums) {
    __shared__ float red[16][132];  // +4 pad: 2-way banks max
    __shared__ int gid[16];
    int tid = threadIdx.x;
    int sl = tid >> 4;   // node slot
    int l = tid & 15;    // 16B chunk (dims 8l..8l+7)
    int n = blockIdx.x * 16 + sl;

    int s = row_ptr[n], e = row_ptr[n + 1];
    union F4H { float4 f; __half2 h[4]; } u;
    float acc[8];
    u.f = Y[(size_t)n * 16 + l];  // self-loop term
#pragma unroll
    for (int q = 0; q < 4; ++q) {
        float2 p = __half22float2(u.h[q]);
        acc[2 * q] = p.x; acc[2 * q + 1] = p.y;
    }
    int i = s;
    for (; i + 1 < e; i += 2) {
        int r0 = adj[i], r1 = adj[i + 1];
        F4H u0, u1;
        u0.f = Y[(size_t)r0 * 16 + l];
        u1.f = Y[(size_t)r1 * 16 + l];
#pragma unroll
        for (int q = 0; q < 4; ++q) {
            float2 p0 = __half22float2(u0.h[q]);
            float2 p1 = __half22float2(u1.h[q]);
            acc[2 * q] += p0.x + p1.x;
            acc[2 * q + 1] += p0.y + p1.y;
        }
    }
    if (i < e) {
        F4H u0; u0.f = Y[(size_t)adj[i] * 16 + l];
#pragma unroll
        for (int q = 0; q < 4; ++q) {
            float2 p0 = __half22float2(u0.h[q]);
            acc[2 * q] += p0.x;
            acc[2 * q + 1] += p0.y;
        }
    }

    float dv = dinv[n];
#pragma unroll
    for (int q = 0; q < 8; ++q) {
        float v = dv * acc[q] + bias[l * 8 + q];
        red[sl][l * 8 + q] = fmaxf(v, 0.f);
    }
    if (l == 0) gid[sl] = batch[n];
    __syncthreads();

    if (tid < DIM) {
        int d = tid;
        float a = 0.f;
        int g = gid[0];
        for (int s2 = 0; s2 < 16; ++s2) {
            int gs = gid[s2];
            if (gs != g) {
                if (a != 0.f) atomicAdd(&sums[g * DIM + d], a);
                a = 0.f; g = gs;
            }
            a += red[s2][d];
        }
        if (a != 0.f) atomicAdd(&sums[g * DIM + d], a);
    }
}

// xg[t][j] = b_ih[j] + b_hh[j] + pooled[t] . w_ih[j]
__global__ __launch_bounds__(512) void k_xgate(const float* __restrict__ sums, const int* __restrict__ start,
                                               const float* __restrict__ w_ih, const float* __restrict__ b_ih,
                                               const float* __restrict__ b_hh, float* __restrict__ xg) {
    __shared__ float4 p4[DIM / 4];
    int t = blockIdx.x, j = threadIdx.x;
    if (j < DIM) {
        int c = start[t + 1] - start[t];
        float inv = 1.0f / fmaxf((float)c, 1.0f);
        ((float*)p4)[j] = sums[t * DIM + j] * inv;
    }
    __syncthreads();
    const float4* w4 = (const float4*)(w_ih + (size_t)j * DIM);
    float acc = b_ih[j] + b_hh[j];
#pragma unroll
    for (int kk = 0; kk < 32; ++kk) {
        float4 w = w4[kk];
        float4 p = p4[kk];
        acc += w.x * p.x + w.y * p.y + w.z * p.z + w.w * p.w;
    }
    xg[t * GATE + j] = acc;
}

// w_hh -> fp16 pair-transposed: w2g[p*512 + j] = (w_hh[j][2p], w_hh[j][2p+1])
__global__ __launch_bounds__(256) void k_wcvt(const float* __restrict__ w_hh, __half2* __restrict__ w2g) {
    int t = blockIdx.x * 256 + threadIdx.x;
    if (t < 64 * GATE) {
        int p = t >> 9, j = t & 511;
        w2g[t] = __floats2half2_rn(w_hh[(size_t)j * DIM + 2 * p], w_hh[(size_t)j * DIM + 2 * p + 1]);
    }
}

// Sequential LSTM + FC. fp16 weights resident in 128 KB LDS (LDSW=1),
// conflict-free lane-consecutive reads; h broadcast; fdot2 MACs.
template <int LDSW>
__global__ __launch_bounds__(512) void k_lstm2(const float* __restrict__ xg, const __half2* __restrict__ w2g,
                                               const float* __restrict__ Wfc, const float* __restrict__ bfc,
                                               float* __restrict__ out) {
    extern __shared__ char smem[];
    f16x2* w2 = (f16x2*)smem;                          // LDSW only
    char* aux = LDSW ? (smem + SMEM_W) : smem;
    __half* h2h = (__half*)aux;                        // 128 halves
    float* gates = (float*)(aux + 256);                // 512 f32
    __half* hsh = (__half*)(aux + 256 + 2048);         // 64*128 halves
    int j = threadIdx.x;

    if (LDSW) {
#pragma unroll 8
        for (int p = 0; p < 64; ++p) {
            union { __half2 h; f16x2 v; } u;
            u.h = w2g[p * GATE + j];   // coalesced read
            w2[p * GATE + j] = u.v;    // conflict-free write
        }
    }
    if (j < DIM) h2h[j] = __float2half(0.f);
    float c = 0.f;
    float xcur = xg[j];
    __syncthreads();

    const f16x2* wrow = LDSW ? (const f16x2*)w2 : (const f16x2*)w2g;
    const float4* h4 = (const float4*)h2h;
    for (int t = 0; t < NG; ++t) {
        float xnext = (t + 1 < NG) ? xg[(t + 1) * GATE + j] : 0.f;
        float acc = xcur;
#pragma unroll
        for (int pc = 0; pc < 8; ++pc) {
            float4 r0 = h4[pc * 2];      // broadcast, 8 h-pairs per chunk
            float4 r1 = h4[pc * 2 + 1];
            f16x2 hc[8];
            hc[0] = f2h2cast(r0.x); hc[1] = f2h2cast(r0.y);
            hc[2] = f2h2cast(r0.z); hc[3] = f2h2cast(r0.w);
            hc[4] = f2h2cast(r1.x); hc[5] = f2h2cast(r1.y);
            hc[6] = f2h2cast(r1.z); hc[7] = f2h2cast(r1.w);
#pragma unroll
            for (int q = 0; q < 8; ++q)
                acc = fdot2f(wrow[(pc * 8 + q) * GATE + j], hc[q], acc);
        }
        gates[j] = acc;
        __syncthreads();
        if (j < DIM) {
            float gi = gates[j], gf = gates[DIM + j], gg = gates[2 * DIM + j], go = gates[3 * DIM + j];
            c = sigf(gf) * c + sigf(gi) * tanhfast(gg);
            float hn = sigf(go) * tanhfast(c);
            h2h[j] = __float2half(hn);
            hsh[t * DIM + j] = __float2half(hn);
        }
        xcur = xnext;
        __syncthreads();
    }

    // FC: out[t][cls] = b_fc[cls] + hs[t] . W_fc[cls]
    for (int o = j; o < NG * 10; o += 512) {
        int t = o / 10, cls = o - t * 10;
        const __half2* hv = (const __half2*)(hsh + t * DIM);
        float acc = bfc[cls];
#pragma unroll
        for (int kk = 0; kk < 64; ++kk) {
            float2 hf = __half22float2(hv[kk]);
            acc += hf.x * Wfc[cls * DIM + 2 * kk] + hf.y * Wfc[cls * DIM + 2 * kk + 1];
        }
        out[o] = acc;
    }
}

extern "C" void kernel_launch(void* const* d_in, const int* in_sizes, int n_in,
                              void* d_out, int out_size, void* d_ws, size_t ws_size,
                              hipStream_t stream) {
    const float* x     = (const float*)d_in[0];
    const int*   ei    = (const int*)d_in[1];
    const int*   batch = (const int*)d_in[2];
    const float* W_gcn = (const float*)d_in[3];
    const float* b_gcn = (const float*)d_in[4];
    const float* w_ih  = (const float*)d_in[5];
    const float* w_hh  = (const float*)d_in[6];
    const float* b_ih  = (const float*)d_in[7];
    const float* b_hh  = (const float*)d_in[8];
    const float* W_fc  = (const float*)d_in[9];
    const float* b_fc  = (const float*)d_in[10];
    float* out = (float*)d_out;

    char* ws = (char*)d_ws;
    __half* yh    = (__half*)ws;                                   // 25.6 MB
    __half* wt16  = (__half*)(ws + (size_t)NNODES * DIM * 2);      // 32 KB (old agg2 slot)
    float*  dinv  = (float*)(ws + (size_t)NNODES * DIM * 4);       // 400 KB
    float*  sums  = dinv + 100096;
    float*  xg    = sums + NG * DIM;
    int*    deg   = (int*)(xg + NG * GATE);
    int*    row_ptr = deg + 100096;
    int*    cursor  = row_ptr + 100096;
    int*    adj     = cursor + 100096;      // 6.4 MB
    int*    start   = adj + NEDGES;
    int*    bsum    = start + 128;
    __half2* w2g    = (__half2*)(bsum + 128);  // 128 KB fp16 LSTM weights

    hipMemsetAsync(deg, 0, NNODES * sizeof(int), stream);
    hipMemsetAsync(sums, 0, NG * DIM * sizeof(float), stream);

    k_deg<<<(NEDGES + 255) / 256, 256, 0, stream>>>(ei, deg);
    k_scan1<<<SCAN_NB, 1024, 0, stream>>>(deg, row_ptr, bsum);
    k_scan2<<<1, 128, 0, stream>>>(bsum, row_ptr, batch, start);
    k_scan3<<<SCAN_NB, 1024, 0, stream>>>(deg, row_ptr, bsum, cursor, dinv);
    for (int p = 0; p < FILL_NPASS; ++p)
        k_fillb<<<(NEDGES + 255) / 256, 256, 0, stream>>>(ei, cursor, adj, p * BUCKET);
    k_wt<<<(DIM * DIM + 255) / 256, 256, 0, stream>>>(W_gcn, wt16);
    k_gemmm<<<(NNODES + 63) / 64, 256, 0, stream>>>(x, wt16, dinv, yh);
    k_gpool<<<NNODES / 16, 256, 0, stream>>>(row_ptr, adj, (const float4*)yh, dinv, b_gcn, batch, sums);
    k_xgate<<<NG, 512, 0, stream>>>(sums, start, w_ih, b_ih, b_hh, xg);
    k_wcvt<<<(64 * GATE + 255) / 256, 256, 0, stream>>>(w_hh, w2g);

    bool lds_ok = hipFuncSetAttribute((const void*)k_lstm2<1>,
                                      hipFuncAttributeMaxDynamicSharedMemorySize,
                                      SMEM_TOTAL) == hipSuccess;
    if (lds_ok)
        k_lstm2<1><<<1, 512, SMEM_TOTAL, stream>>>(xg, w2g, W_fc, b_fc, out);
    else
        k_lstm2<0><<<1, 512, SMEM_AUX, stream>>>(xg, w2g, W_fc, b_fc, out);
}

// Round 10
// 364.291 us; speedup vs baseline: 1.3285x; 1.0486x over previous
//
#include <hip/hip_runtime.h>
#include <hip/hip_fp16.h>
#include <math.h>

#define NNODES 100000
#define NEDGES 1600000
#define DIM 128
#define NG 64
#define GATE 512
#define SCAN_NB 98  // ceil(NNODES / 1024)
#define FILL_NPASS 4
#define BUCKET ((NNODES + FILL_NPASS - 1) / FILL_NPASS)  // 25000

// k_lstm2 dynamic LDS layout
#define SMEM_W   131072                       // 512 rows x 16 chunks x 16 B (fp16, swizzled)
#define SMEM_AUX (256 + 2048 + 16384)         // h2h + gates + hsh
#define SMEM_TOTAL (SMEM_W + SMEM_AUX)        // 149760 <= 160K/CU

typedef _Float16 f16x2 __attribute__((ext_vector_type(2)));
typedef _Float16 half8_t __attribute__((ext_vector_type(8)));
typedef float f32x4 __attribute__((ext_vector_type(4)));

__device__ __forceinline__ f16x2 f2h2cast(float f) {
    union U { float f; f16x2 h; } u; u.f = f; return u.h;
}
__device__ __forceinline__ float fdot2f(f16x2 a, f16x2 b, float c) {
#if __has_builtin(__builtin_amdgcn_fdot2)
    return __builtin_amdgcn_fdot2(a, b, c, false);
#else
    return c + (float)a[0] * (float)b[0] + (float)a[1] * (float)b[1];
#endif
}

// fast sigmoid/tanh: v_exp_f32 + v_rcp_f32 (absmax headroom is ~100x)
__device__ __forceinline__ float sigf(float x) {
    return __builtin_amdgcn_rcpf(1.0f + __expf(-x));
}
__device__ __forceinline__ float tanhfast(float x) {
    float e = __expf(2.0f * x);
    return 1.0f - 2.0f * __builtin_amdgcn_rcpf(e + 1.0f);
}

// in-degree count by col (int atomics)
__global__ __launch_bounds__(256) void k_deg(const int* __restrict__ ei, int* __restrict__ deg) {
    int e = blockIdx.x * 256 + threadIdx.x;
    if (e < NEDGES) atomicAdd(&deg[ei[NEDGES + e]], 1);
}

// stage 1: per-block exclusive scan of deg; block sums out
__global__ __launch_bounds__(1024) void k_scan1(const int* __restrict__ deg, int* __restrict__ row_ptr,
                                                int* __restrict__ bsum) {
    __shared__ int ls[1024];
    int tid = threadIdx.x;
    int n = blockIdx.x * 1024 + tid;
    int v = (n < NNODES) ? deg[n] : 0;
    ls[tid] = v;
    __syncthreads();
    for (int off = 1; off < 1024; off <<= 1) {
        int t = (tid >= off) ? ls[tid - off] : 0;
        __syncthreads();
        ls[tid] += t;
        __syncthreads();
    }
    if (n < NNODES) row_ptr[n] = ls[tid] - v;  // exclusive within block
    if (tid == 1023) bsum[blockIdx.x] = ls[1023];
}

// stage 2: exclusive scan of block sums + graph segment bounds (batch sorted)
__global__ __launch_bounds__(128) void k_scan2(int* __restrict__ bsum, int* __restrict__ row_ptr,
                                               const int* __restrict__ batch, int* __restrict__ start) {
    __shared__ int ls[128];
    int tid = threadIdx.x;
    int v = (tid < SCAN_NB) ? bsum[tid] : 0;
    ls[tid] = v;
    __syncthreads();
    for (int off = 1; off < 128; off <<= 1) {
        int t = (tid >= off) ? ls[tid - off] : 0;
        __syncthreads();
        ls[tid] += t;
        __syncthreads();
    }
    if (tid < SCAN_NB) bsum[tid] = ls[tid] - v;  // exclusive block offsets
    if (tid == 127) row_ptr[NNODES] = ls[127];
    // graph bounds via binary search
    if (tid <= NG) {
        int lo = 0, hi = NNODES;
        while (lo < hi) {
            int mid = (lo + hi) >> 1;
            if (batch[mid] < tid) lo = mid + 1; else hi = mid;
        }
        start[tid] = lo;
    }
}

// stage 3: add block offsets; init cursor = row_ptr; compute dinv
__global__ __launch_bounds__(1024) void k_scan3(const int* __restrict__ deg, int* __restrict__ row_ptr,
                                                const int* __restrict__ bsum, int* __restrict__ cursor,
                                                float* __restrict__ dinv) {
    int n = blockIdx.x * 1024 + threadIdx.x;
    if (n < NNODES) {
        int rp = row_ptr[n] + bsum[blockIdx.x];
        row_ptr[n] = rp;
        cursor[n] = rp;
        dinv[n] = rsqrtf((float)deg[n] + 1.0f);
    }
}

// adj[cursor[col]++] = row, only for cols in [b0, b0+BUCKET): temporal
// bucketing keeps the adj write window at 1.6 MB -> lines fill in L2
__global__ __launch_bounds__(256) void k_fillb(const int* __restrict__ ei, int* __restrict__ cursor,
                                               int* __restrict__ adj, int b0) {
    int e = blockIdx.x * 256 + threadIdx.x;
    if (e < NEDGES) {
        int col = ei[NEDGES + e];
        if (col >= b0 && col < b0 + BUCKET) {
            int row = ei[e];
            int pos = atomicAdd(&cursor[col], 1);
            adj[pos] = row;
        }
    }
}

// fused weight prep: w_hh -> fp16 row-major; W_gcn -> fp16 transposed [d][k]
__global__ __launch_bounds__(256) void k_wprep(const float* __restrict__ W_gcn, const float* __restrict__ w_hh,
                                               __half* __restrict__ Wt, __half* __restrict__ whh16) {
    int t = blockIdx.x * 256 + threadIdx.x;
    if (t < GATE * DIM) {
        whh16[t] = __float2half(w_hh[t]);
    } else {
        int idx = t - GATE * DIM;
        if (idx < DIM * DIM) {
            int d = idx >> 7, k = idx & 127;
            Wt[idx] = __float2half(W_gcn[k * DIM + d]);
        }
    }
}

// y[n] = (x[n] @ W) * dinv[n] via v_mfma_f32_16x16x32_f16, fp16 out.
// Block = 256 thr = 4 waves; wave wt owns rows [rb+wt*16, +16), all 128 cols.
__global__ __launch_bounds__(256) void k_gemmm(const float* __restrict__ x, const __half* __restrict__ Wt,
                                               const float* __restrict__ dinv, __half* __restrict__ yh) {
    int tid = threadIdx.x;
    int wt = tid >> 6, lane = tid & 63;
    int lr = lane & 15, kgrp = lane >> 4;
    int rb = blockIdx.x * 64 + wt * 16;

    int rowA = rb + lr;
    if (rowA >= NNODES) rowA = NNODES - 1;
    const float4* x4 = (const float4*)x;

    f32x4 acc[8];
#pragma unroll
    for (int ct = 0; ct < 8; ++ct) acc[ct] = (f32x4){0.f, 0.f, 0.f, 0.f};

#pragma unroll
    for (int c = 0; c < 4; ++c) {
        int kb = c * 32 + kgrp * 8;
        float4 v0 = x4[(size_t)rowA * 32 + (kb >> 2)];
        float4 v1 = x4[(size_t)rowA * 32 + (kb >> 2) + 1];
        half8_t a;
        a[0] = (_Float16)v0.x; a[1] = (_Float16)v0.y; a[2] = (_Float16)v0.z; a[3] = (_Float16)v0.w;
        a[4] = (_Float16)v1.x; a[5] = (_Float16)v1.y; a[6] = (_Float16)v1.z; a[7] = (_Float16)v1.w;
#pragma unroll
        for (int ct = 0; ct < 8; ++ct) {
            int col = ct * 16 + lr;
            half8_t b = *(const half8_t*)(Wt + (size_t)col * DIM + kb);
            acc[ct] = __builtin_amdgcn_mfma_f32_16x16x32_f16(a, b, acc[ct], 0, 0, 0);
        }
    }

    int rowbase = rb + kgrp * 4;
    float dv[4];
    bool ok[4];
#pragma unroll
    for (int r = 0; r < 4; ++r) {
        int row = rowbase + r;
        ok[r] = row < NNODES;
        dv[r] = ok[r] ? dinv[row] : 0.f;
    }
#pragma unroll
    for (int ct = 0; ct < 8; ++ct) {
#pragma unroll
        for (int r = 0; r < 4; ++r) {
            if (ok[r])
                yh[(size_t)(rowbase + r) * DIM + ct * 16 + lr] = __float2half(acc[ct][r] * dv[r]);
        }
    }
}

// Fused gather + ReLU + mean-pool partial sums (16 nodes/block, exact grid).
__global__ __launch_bounds__(256) void k_gpool(const int* __restrict__ row_ptr, const int* __restrict__ adj,
                                               const float4* __restrict__ Y, const float* __restrict__ dinv,
                                               const float* __restrict__ bias, const int* __restrict__ batch,
                                               float* __restrict__ sums) {
    __shared__ float red[16][132];  // +4 pad
    __shared__ int gid[16];
    int tid = threadIdx.x;
    int sl = tid >> 4;   // node slot
    int l = tid & 15;    // 16B chunk (dims 8l..8l+7)
    int n = blockIdx.x * 16 + sl;

    int s = row_ptr[n], e = row_ptr[n + 1];
    union F4H { float4 f; __half2 h[4]; } u;
    float acc[8];
    u.f = Y[(size_t)n * 16 + l];  // self-loop term
#pragma unroll
    for (int q = 0; q < 4; ++q) {
        float2 p = __half22float2(u.h[q]);
        acc[2 * q] = p.x; acc[2 * q + 1] = p.y;
    }
    int i = s;
    for (; i + 1 < e; i += 2) {
        int r0 = adj[i], r1 = adj[i + 1];
        F4H u0, u1;
        u0.f = Y[(size_t)r0 * 16 + l];
        u1.f = Y[(size_t)r1 * 16 + l];
#pragma unroll
        for (int q = 0; q < 4; ++q) {
            float2 p0 = __half22float2(u0.h[q]);
            float2 p1 = __half22float2(u1.h[q]);
            acc[2 * q] += p0.x + p1.x;
            acc[2 * q + 1] += p0.y + p1.y;
        }
    }
    if (i < e) {
        F4H u0; u0.f = Y[(size_t)adj[i] * 16 + l];
#pragma unroll
        for (int q = 0; q < 4; ++q) {
            float2 p0 = __half22float2(u0.h[q]);
            acc[2 * q] += p0.x;
            acc[2 * q + 1] += p0.y;
        }
    }

    float dv = dinv[n];
#pragma unroll
    for (int q = 0; q < 8; ++q) {
        float v = dv * acc[q] + bias[l * 8 + q];
        red[sl][l * 8 + q] = fmaxf(v, 0.f);
    }
    if (l == 0) gid[sl] = batch[n];
    __syncthreads();

    if (tid < DIM) {
        int d = tid;
        float a = 0.f;
        int g = gid[0];
        for (int s2 = 0; s2 < 16; ++s2) {
            int gs = gid[s2];
            if (gs != g) {
                if (a != 0.f) atomicAdd(&sums[g * DIM + d], a);
                a = 0.f; g = gs;
            }
            a += red[s2][d];
        }
        if (a != 0.f) atomicAdd(&sums[g * DIM + d], a);
    }
}

// xg[t][j] = b_ih[j] + b_hh[j] + pooled[t] . w_ih[j]
__global__ __launch_bounds__(512) void k_xgate(const float* __restrict__ sums, const int* __restrict__ start,
                                               const float* __restrict__ w_ih, const float* __restrict__ b_ih,
                                               const float* __restrict__ b_hh, float* __restrict__ xg) {
    __shared__ float4 p4[DIM / 4];
    int t = blockIdx.x, j = threadIdx.x;
    if (j < DIM) {
        int c = start[t + 1] - start[t];
        float inv = 1.0f / fmaxf((float)c, 1.0f);
        ((float*)p4)[j] = sums[t * DIM + j] * inv;
    }
    __syncthreads();
    const float4* w4 = (const float4*)(w_ih + (size_t)j * DIM);
    float acc = b_ih[j] + b_hh[j];
#pragma unroll
    for (int kk = 0; kk < 32; ++kk) {
        float4 w = w4[kk];
        float4 p = p4[kk];
        acc += w.x * p.x + w.y * p.y + w.z * p.z + w.w * p.w;
    }
    xg[t * GATE + j] = acc;
}

// Sequential LSTM + FC. fp16 weights in 128 KB LDS, read as ds_read_b128.
// Row j chunk c lives at LDS slot j*16 + (c ^ (j&15)): the XOR spreads the
// 16 chunk slots across lanes so each b128 instr runs at the 8-bank-cycle
// floor (1024 B / 128 B-per-cy) instead of all lanes stacking on one bank
// group. R9 was b32 issue-bound: 512 instr/step x 5.8 cy = 2970 cy/step;
// this is 128 instr/step -> ~1024 bank-cy/step.
template <int LDSW>
__global__ __launch_bounds__(512) void k_lstm2(const float* __restrict__ xg, const __half* __restrict__ whh16,
                                               const float* __restrict__ Wfc, const float* __restrict__ bfc,
                                               float* __restrict__ out) {
    extern __shared__ char smem[];
    half8_t* w8L = (half8_t*)smem;                     // LDSW only
    char* aux = LDSW ? (smem + SMEM_W) : smem;
    __half* h2h = (__half*)aux;                        // 128 halves
    float* gates = (float*)(aux + 256);                // 512 f32
    __half* hsh = (__half*)(aux + 256 + 2048);         // 64*128 halves
    int j = threadIdx.x;
    int sw = j & 15;

    if (LDSW) {
#pragma unroll
        for (int c = 0; c < 16; ++c) {
            half8_t g = *(const half8_t*)(whh16 + (size_t)j * DIM + 8 * c);
            w8L[j * 16 + (c ^ sw)] = g;
        }
    }
    if (j < DIM) h2h[j] = __float2half(0.f);
    float c = 0.f;
    float xcur = xg[j];
    __syncthreads();

    const half8_t* wrow = LDSW ? (const half8_t*)w8L : (const half8_t*)whh16;
    const float4* h4 = (const float4*)h2h;
    for (int t = 0; t < NG; ++t) {
        float xnext = (t + 1 < NG) ? xg[(t + 1) * GATE + j] : 0.f;
        float acc = xcur;
#pragma unroll
        for (int cc = 0; cc < 16; ++cc) {
            int idx = LDSW ? (j * 16 + (cc ^ sw)) : (j * 16 + cc);
            union { half8_t v; f16x2 p[4]; } w;
            w.v = wrow[idx];
            float4 hr = h4[cc];  // broadcast: halves 8cc..8cc+7
            acc = fdot2f(w.p[0], f2h2cast(hr.x), acc);
            acc = fdot2f(w.p[1], f2h2cast(hr.y), acc);
            acc = fdot2f(w.p[2], f2h2cast(hr.z), acc);
            acc = fdot2f(w.p[3], f2h2cast(hr.w), acc);
        }
        gates[j] = acc;
        __syncthreads();
        if (j < DIM) {
            float gi = gates[j], gf = gates[DIM + j], gg = gates[2 * DIM + j], go = gates[3 * DIM + j];
            c = sigf(gf) * c + sigf(gi) * tanhfast(gg);
            float hn = sigf(go) * tanhfast(c);
            h2h[j] = __float2half(hn);
            hsh[t * DIM + j] = __float2half(hn);
        }
        xcur = xnext;
        __syncthreads();
    }

    // FC: out[t][cls] = b_fc[cls] + hs[t] . W_fc[cls]
    for (int o = j; o < NG * 10; o += 512) {
        int t = o / 10, cls = o - t * 10;
        const __half2* hv = (const __half2*)(hsh + t * DIM);
        float acc = bfc[cls];
#pragma unroll
        for (int kk = 0; kk < 64; ++kk) {
            float2 hf = __half22float2(hv[kk]);
            acc += hf.x * Wfc[cls * DIM + 2 * kk] + hf.y * Wfc[cls * DIM + 2 * kk + 1];
        }
        out[o] = acc;
    }
}

extern "C" void kernel_launch(void* const* d_in, const int* in_sizes, int n_in,
                              void* d_out, int out_size, void* d_ws, size_t ws_size,
                              hipStream_t stream) {
    const float* x     = (const float*)d_in[0];
    const int*   ei    = (const int*)d_in[1];
    const int*   batch = (const int*)d_in[2];
    const float* W_gcn = (const float*)d_in[3];
    const float* b_gcn = (const float*)d_in[4];
    const float* w_ih  = (const float*)d_in[5];
    const float* w_hh  = (const float*)d_in[6];
    const float* b_ih  = (const float*)d_in[7];
    const float* b_hh  = (const float*)d_in[8];
    const float* W_fc  = (const float*)d_in[9];
    const float* b_fc  = (const float*)d_in[10];
    float* out = (float*)d_out;

    char* ws = (char*)d_ws;
    __half* yh    = (__half*)ws;                                   // 25.6 MB
    __half* wt16  = (__half*)(ws + (size_t)NNODES * DIM * 2);      // 32 KB
    float*  dinv  = (float*)(ws + (size_t)NNODES * DIM * 4);       // 400 KB
    float*  sums  = dinv + 100096;
    float*  xg    = sums + NG * DIM;
    int*    deg   = (int*)(xg + NG * GATE);
    int*    row_ptr = deg + 100096;
    int*    cursor  = row_ptr + 100096;
    int*    adj     = cursor + 100096;      // 6.4 MB
    int*    start   = adj + NEDGES;
    int*    bsum    = start + 128;
    __half* whh16   = (__half*)(bsum + 128);  // 128 KB fp16 LSTM weights (row-major)

    hipMemsetAsync(deg, 0, NNODES * sizeof(int), stream);
    hipMemsetAsync(sums, 0, NG * DIM * sizeof(float), stream);

    k_deg<<<(NEDGES + 255) / 256, 256, 0, stream>>>(ei, deg);
    k_scan1<<<SCAN_NB, 1024, 0, stream>>>(deg, row_ptr, bsum);
    k_scan2<<<1, 128, 0, stream>>>(bsum, row_ptr, batch, start);
    k_scan3<<<SCAN_NB, 1024, 0, stream>>>(deg, row_ptr, bsum, cursor, dinv);
    for (int p = 0; p < FILL_NPASS; ++p)
        k_fillb<<<(NEDGES + 255) / 256, 256, 0, stream>>>(ei, cursor, adj, p * BUCKET);
    k_wprep<<<(GATE * DIM + DIM * DIM + 255) / 256, 256, 0, stream>>>(W_gcn, w_hh, wt16, whh16);
    k_gemmm<<<(NNODES + 63) / 64, 256, 0, stream>>>(x, wt16, dinv, yh);
    k_gpool<<<NNODES / 16, 256, 0, stream>>>(row_ptr, adj, (const float4*)yh, dinv, b_gcn, batch, sums);
    k_xgate<<<NG, 512, 0, stream>>>(sums, start, w_ih, b_ih, b_hh, xg);

    bool lds_ok = hipFuncSetAttribute((const void*)k_lstm2<1>,
                                      hipFuncAttributeMaxDynamicSharedMemorySize,
                                      SMEM_TOTAL) == hipSuccess;
    if (lds_ok)
        k_lstm2<1><<<1, 512, SMEM_TOTAL, stream>>>(xg, whh16, W_fc, b_fc, out);
    else
        k_lstm2<0><<<1, 512, SMEM_AUX, stream>>>(xg, whh16, W_fc, b_fc, out);
}

// Round 11
// 310.326 us; speedup vs baseline: 1.5595x; 1.1739x over previous
//
#include <hip/hip_runtime.h>
#include <hip/hip_fp16.h>
#include <math.h>

#define NNODES 100000
#define NEDGES 1600000
#define DIM 128
#define NG 64
#define GATE 512
#define SCAN_NB 98  // ceil(NNODES / 1024)
#define FILL_NPASS 4
#define BUCKET ((NNODES + FILL_NPASS - 1) / FILL_NPASS)  // 25000

// degree histogram
#define HG 128           // partial-histogram blocks
#define HW 25024         // u32 words per partial (4 packed u8 cols each)
#define HSMEM (HW * 4)   // 100096 B dynamic LDS

// k_lstm2 dynamic LDS layout
#define SMEM_W   131072                       // 512 rows x 16 chunks x 16 B (fp16, swizzled)
#define SMEM_AUX (256 + 2048 + 16384)         // h2h + gates + hsh
#define SMEM_TOTAL (SMEM_W + SMEM_AUX)        // 149760 <= 160K/CU

typedef _Float16 f16x2 __attribute__((ext_vector_type(2)));
typedef _Float16 half8_t __attribute__((ext_vector_type(8)));
typedef float f32x4 __attribute__((ext_vector_type(4)));

__device__ __forceinline__ f16x2 f2h2cast(float f) {
    union U { float f; f16x2 h; } u; u.f = f; return u.h;
}
__device__ __forceinline__ float fdot2f(f16x2 a, f16x2 b, float c) {
#if __has_builtin(__builtin_amdgcn_fdot2)
    return __builtin_amdgcn_fdot2(a, b, c, false);
#else
    return c + (float)a[0] * (float)b[0] + (float)a[1] * (float)b[1];
#endif
}

// fast sigmoid/tanh: v_exp_f32 + v_rcp_f32 (absmax headroom is ~100x)
__device__ __forceinline__ float sigf(float x) {
    return __builtin_amdgcn_rcpf(1.0f + __expf(-x));
}
__device__ __forceinline__ float tanhfast(float x) {
    float e = __expf(2.0f * x);
    return 1.0f - 2.0f * __builtin_amdgcn_rcpf(e + 1.0f);
}

// ---- degree: per-block LDS u8-packed histogram, NO global atomics ----
// block b handles edges [b*12500, (b+1)*12500); per-block per-col count <= ~8
__global__ __launch_bounds__(1024) void k_deghist(const int* __restrict__ ei, unsigned* __restrict__ partial) {
    extern __shared__ unsigned hist[];  // HW words
    int tid = threadIdx.x;
    for (int i = tid; i < HW; i += 1024) hist[i] = 0u;
    __syncthreads();
    int e0 = blockIdx.x * (NEDGES / HG);
    int e1 = e0 + (NEDGES / HG);
    for (int e = e0 + tid; e < e1; e += 1024) {
        int col = ei[NEDGES + e];
        atomicAdd(&hist[col >> 2], 1u << ((col & 3) * 8));
    }
    __syncthreads();
    unsigned* dst = partial + (size_t)blockIdx.x * HW;
    for (int i = tid; i < HW; i += 1024) dst[i] = hist[i];
}

// fallback if 100KB dynamic LDS unavailable: plain atomic count
__global__ __launch_bounds__(256) void k_deg(const int* __restrict__ ei, int* __restrict__ deg) {
    int e = blockIdx.x * 256 + threadIdx.x;
    if (e < NEDGES) atomicAdd(&deg[ei[NEDGES + e]], 1);
}

// sum HG partials (u32 adds; byte lanes <= deg ~60, no carry), emit deg + dinv
__global__ __launch_bounds__(256) void k_degred(const unsigned* __restrict__ partial, int* __restrict__ deg,
                                                float* __restrict__ dinv) {
    int w = blockIdx.x * 256 + threadIdx.x;  // packed word = 4 nodes
    if (w >= NNODES / 4) return;
    unsigned s = 0;
    for (int b = 0; b < HG; ++b) s += partial[(size_t)b * HW + w];
    int4 d;
    d.x = s & 255; d.y = (s >> 8) & 255; d.z = (s >> 16) & 255; d.w = (int)(s >> 24);
    ((int4*)deg)[w] = d;
    float4 dv;
    dv.x = rsqrtf((float)d.x + 1.f);
    dv.y = rsqrtf((float)d.y + 1.f);
    dv.z = rsqrtf((float)d.z + 1.f);
    dv.w = rsqrtf((float)d.w + 1.f);
    ((float4*)dinv)[w] = dv;
}

// dinv for the atomic fallback path
__global__ __launch_bounds__(256) void k_dinv(const int* __restrict__ deg, float* __restrict__ dinv) {
    int n = blockIdx.x * 256 + threadIdx.x;
    if (n < NNODES) dinv[n] = rsqrtf((float)deg[n] + 1.0f);
}

// stage 1: per-block exclusive scan of deg; block sums out
__global__ __launch_bounds__(1024) void k_scan1(const int* __restrict__ deg, int* __restrict__ row_ptr,
                                                int* __restrict__ bsum) {
    __shared__ int ls[1024];
    int tid = threadIdx.x;
    int n = blockIdx.x * 1024 + tid;
    int v = (n < NNODES) ? deg[n] : 0;
    ls[tid] = v;
    __syncthreads();
    for (int off = 1; off < 1024; off <<= 1) {
        int t = (tid >= off) ? ls[tid - off] : 0;
        __syncthreads();
        ls[tid] += t;
        __syncthreads();
    }
    if (n < NNODES) row_ptr[n] = ls[tid] - v;  // exclusive within block
    if (tid == 1023) bsum[blockIdx.x] = ls[1023];
}

// stage 2: exclusive scan of block sums + graph segment bounds (batch sorted)
__global__ __launch_bounds__(128) void k_scan2(int* __restrict__ bsum, int* __restrict__ row_ptr,
                                               const int* __restrict__ batch, int* __restrict__ start) {
    __shared__ int ls[128];
    int tid = threadIdx.x;
    int v = (tid < SCAN_NB) ? bsum[tid] : 0;
    ls[tid] = v;
    __syncthreads();
    for (int off = 1; off < 128; off <<= 1) {
        int t = (tid >= off) ? ls[tid - off] : 0;
        __syncthreads();
        ls[tid] += t;
        __syncthreads();
    }
    if (tid < SCAN_NB) bsum[tid] = ls[tid] - v;  // exclusive block offsets
    if (tid == 127) row_ptr[NNODES] = ls[127];
    // graph bounds via binary search
    if (tid <= NG) {
        int lo = 0, hi = NNODES;
        while (lo < hi) {
            int mid = (lo + hi) >> 1;
            if (batch[mid] < tid) lo = mid + 1; else hi = mid;
        }
        start[tid] = lo;
    }
}

// stage 3: add block offsets; init cursor = row_ptr
__global__ __launch_bounds__(1024) void k_scan3(int* __restrict__ row_ptr, const int* __restrict__ bsum,
                                                int* __restrict__ cursor) {
    int n = blockIdx.x * 1024 + threadIdx.x;
    if (n < NNODES) {
        int rp = row_ptr[n] + bsum[blockIdx.x];
        row_ptr[n] = rp;
        cursor[n] = rp;
    }
}

// adj[cursor[col]++] = row, only for cols in [b0, b0+BUCKET): temporal
// bucketing keeps the adj write window at 1.6 MB -> lines fill in L2
__global__ __launch_bounds__(256) void k_fillb(const int* __restrict__ ei, int* __restrict__ cursor,
                                               int* __restrict__ adj, int b0) {
    int e = blockIdx.x * 256 + threadIdx.x;
    if (e < NEDGES) {
        int col = ei[NEDGES + e];
        if (col >= b0 && col < b0 + BUCKET) {
            int row = ei[e];
            int pos = atomicAdd(&cursor[col], 1);
            adj[pos] = row;
        }
    }
}

// fused weight prep: w_hh -> fp16 row-major; W_gcn -> fp16 transposed [d][k]
__global__ __launch_bounds__(256) void k_wprep(const float* __restrict__ W_gcn, const float* __restrict__ w_hh,
                                               __half* __restrict__ Wt, __half* __restrict__ whh16) {
    int t = blockIdx.x * 256 + threadIdx.x;
    if (t < GATE * DIM) {
        whh16[t] = __float2half(w_hh[t]);
    } else {
        int idx = t - GATE * DIM;
        if (idx < DIM * DIM) {
            int d = idx >> 7, k = idx & 127;
            Wt[idx] = __float2half(W_gcn[k * DIM + d]);
        }
    }
}

// y[n] = (x[n] @ W) * dinv[n] via v_mfma_f32_16x16x32_f16, fp16 out.
__global__ __launch_bounds__(256) void k_gemmm(const float* __restrict__ x, const __half* __restrict__ Wt,
                                               const float* __restrict__ dinv, __half* __restrict__ yh) {
    int tid = threadIdx.x;
    int wt = tid >> 6, lane = tid & 63;
    int lr = lane & 15, kgrp = lane >> 4;
    int rb = blockIdx.x * 64 + wt * 16;

    int rowA = rb + lr;
    if (rowA >= NNODES) rowA = NNODES - 1;
    const float4* x4 = (const float4*)x;

    f32x4 acc[8];
#pragma unroll
    for (int ct = 0; ct < 8; ++ct) acc[ct] = (f32x4){0.f, 0.f, 0.f, 0.f};

#pragma unroll
    for (int c = 0; c < 4; ++c) {
        int kb = c * 32 + kgrp * 8;
        float4 v0 = x4[(size_t)rowA * 32 + (kb >> 2)];
        float4 v1 = x4[(size_t)rowA * 32 + (kb >> 2) + 1];
        half8_t a;
        a[0] = (_Float16)v0.x; a[1] = (_Float16)v0.y; a[2] = (_Float16)v0.z; a[3] = (_Float16)v0.w;
        a[4] = (_Float16)v1.x; a[5] = (_Float16)v1.y; a[6] = (_Float16)v1.z; a[7] = (_Float16)v1.w;
#pragma unroll
        for (int ct = 0; ct < 8; ++ct) {
            int col = ct * 16 + lr;
            half8_t b = *(const half8_t*)(Wt + (size_t)col * DIM + kb);
            acc[ct] = __builtin_amdgcn_mfma_f32_16x16x32_f16(a, b, acc[ct], 0, 0, 0);
        }
    }

    int rowbase = rb + kgrp * 4;
    float dv[4];
    bool ok[4];
#pragma unroll
    for (int r = 0; r < 4; ++r) {
        int row = rowbase + r;
        ok[r] = row < NNODES;
        dv[r] = ok[r] ? dinv[row] : 0.f;
    }
#pragma unroll
    for (int ct = 0; ct < 8; ++ct) {
#pragma unroll
        for (int r = 0; r < 4; ++r) {
            if (ok[r])
                yh[(size_t)(rowbase + r) * DIM + ct * 16 + lr] = __float2half(acc[ct][r] * dv[r]);
        }
    }
}

// Fused gather + ReLU + mean-pool partial sums (16 nodes/block, exact grid).
__global__ __launch_bounds__(256) void k_gpool(const int* __restrict__ row_ptr, const int* __restrict__ adj,
                                               const float4* __restrict__ Y, const float* __restrict__ dinv,
                                               const float* __restrict__ bias, const int* __restrict__ batch,
                                               float* __restrict__ sums) {
    __shared__ float red[16][132];  // +4 pad
    __shared__ int gid[16];
    int tid = threadIdx.x;
    int sl = tid >> 4;   // node slot
    int l = tid & 15;    // 16B chunk (dims 8l..8l+7)
    int n = blockIdx.x * 16 + sl;

    int s = row_ptr[n], e = row_ptr[n + 1];
    union F4H { float4 f; __half2 h[4]; } u;
    float acc[8];
    u.f = Y[(size_t)n * 16 + l];  // self-loop term
#pragma unroll
    for (int q = 0; q < 4; ++q) {
        float2 p = __half22float2(u.h[q]);
        acc[2 * q] = p.x; acc[2 * q + 1] = p.y;
    }
    int i = s;
    for (; i + 1 < e; i += 2) {
        int r0 = adj[i], r1 = adj[i + 1];
        F4H u0, u1;
        u0.f = Y[(size_t)r0 * 16 + l];
        u1.f = Y[(size_t)r1 * 16 + l];
#pragma unroll
        for (int q = 0; q < 4; ++q) {
            float2 p0 = __half22float2(u0.h[q]);
            float2 p1 = __half22float2(u1.h[q]);
            acc[2 * q] += p0.x + p1.x;
            acc[2 * q + 1] += p0.y + p1.y;
        }
    }
    if (i < e) {
        F4H u0; u0.f = Y[(size_t)adj[i] * 16 + l];
#pragma unroll
        for (int q = 0; q < 4; ++q) {
            float2 p0 = __half22float2(u0.h[q]);
            acc[2 * q] += p0.x;
            acc[2 * q + 1] += p0.y;
        }
    }

    float dv = dinv[n];
#pragma unroll
    for (int q = 0; q < 8; ++q) {
        float v = dv * acc[q] + bias[l * 8 + q];
        red[sl][l * 8 + q] = fmaxf(v, 0.f);
    }
    if (l == 0) gid[sl] = batch[n];
    __syncthreads();

    if (tid < DIM) {
        int d = tid;
        float a = 0.f;
        int g = gid[0];
        for (int s2 = 0; s2 < 16; ++s2) {
            int gs = gid[s2];
            if (gs != g) {
                if (a != 0.f) atomicAdd(&sums[g * DIM + d], a);
                a = 0.f; g = gs;
            }
            a += red[s2][d];
        }
        if (a != 0.f) atomicAdd(&sums[g * DIM + d], a);
    }
}

// xg[t][j] = b_ih[j] + b_hh[j] + pooled[t] . w_ih[j]
__global__ __launch_bounds__(512) void k_xgate(const float* __restrict__ sums, const int* __restrict__ start,
                                               const float* __restrict__ w_ih, const float* __restrict__ b_ih,
                                               const float* __restrict__ b_hh, float* __restrict__ xg) {
    __shared__ float4 p4[DIM / 4];
    int t = blockIdx.x, j = threadIdx.x;
    if (j < DIM) {
        int c = start[t + 1] - start[t];
        float inv = 1.0f / fmaxf((float)c, 1.0f);
        ((float*)p4)[j] = sums[t * DIM + j] * inv;
    }
    __syncthreads();
    const float4* w4 = (const float4*)(w_ih + (size_t)j * DIM);
    float acc = b_ih[j] + b_hh[j];
#pragma unroll
    for (int kk = 0; kk < 32; ++kk) {
        float4 w = w4[kk];
        float4 p = p4[kk];
        acc += w.x * p.x + w.y * p.y + w.z * p.z + w.w * p.w;
    }
    xg[t * GATE + j] = acc;
}

// Sequential LSTM + FC. fp16 weights in 128 KB LDS, ds_read_b128 with XOR
// chunk swizzle (R10: 77 -> ~40 us; b32 was issue-bound at 512 instr/step).
template <int LDSW>
__global__ __launch_bounds__(512) void k_lstm2(const float* __restrict__ xg, const __half* __restrict__ whh16,
                                               const float* __restrict__ Wfc, const float* __restrict__ bfc,
                                               float* __restrict__ out) {
    extern __shared__ char smem[];
    half8_t* w8L = (half8_t*)smem;                     // LDSW only
    char* aux = LDSW ? (smem + SMEM_W) : smem;
    __half* h2h = (__half*)aux;                        // 128 halves
    float* gates = (float*)(aux + 256);                // 512 f32
    __half* hsh = (__half*)(aux + 256 + 2048);         // 64*128 halves
    int j = threadIdx.x;
    int sw = j & 15;

    if (LDSW) {
#pragma unroll
        for (int c = 0; c < 16; ++c) {
            half8_t g = *(const half8_t*)(whh16 + (size_t)j * DIM + 8 * c);
            w8L[j * 16 + (c ^ sw)] = g;
        }
    }
    if (j < DIM) h2h[j] = __float2half(0.f);
    float c = 0.f;
    float xcur = xg[j];
    __syncthreads();

    const half8_t* wrow = LDSW ? (const half8_t*)w8L : (const half8_t*)whh16;
    const float4* h4 = (const float4*)h2h;
    for (int t = 0; t < NG; ++t) {
        float xnext = (t + 1 < NG) ? xg[(t + 1) * GATE + j] : 0.f;
        float acc = xcur;
#pragma unroll
        for (int cc = 0; cc < 16; ++cc) {
            int idx = LDSW ? (j * 16 + (cc ^ sw)) : (j * 16 + cc);
            union { half8_t v; f16x2 p[4]; } w;
            w.v = wrow[idx];
            float4 hr = h4[cc];  // broadcast: halves 8cc..8cc+7
            acc = fdot2f(w.p[0], f2h2cast(hr.x), acc);
            acc = fdot2f(w.p[1], f2h2cast(hr.y), acc);
            acc = fdot2f(w.p[2], f2h2cast(hr.z), acc);
            acc = fdot2f(w.p[3], f2h2cast(hr.w), acc);
        }
        gates[j] = acc;
        __syncthreads();
        if (j < DIM) {
            float gi = gates[j], gf = gates[DIM + j], gg = gates[2 * DIM + j], go = gates[3 * DIM + j];
            c = sigf(gf) * c + sigf(gi) * tanhfast(gg);
            float hn = sigf(go) * tanhfast(c);
            h2h[j] = __float2half(hn);
            hsh[t * DIM + j] = __float2half(hn);
        }
        xcur = xnext;
        __syncthreads();
    }

    // FC: out[t][cls] = b_fc[cls] + hs[t] . W_fc[cls]
    for (int o = j; o < NG * 10; o += 512) {
        int t = o / 10, cls = o - t * 10;
        const __half2* hv = (const __half2*)(hsh + t * DIM);
        float acc = bfc[cls];
#pragma unroll
        for (int kk = 0; kk < 64; ++kk) {
            float2 hf = __half22float2(hv[kk]);
            acc += hf.x * Wfc[cls * DIM + 2 * kk] + hf.y * Wfc[cls * DIM + 2 * kk + 1];
        }
        out[o] = acc;
    }
}

extern "C" void kernel_launch(void* const* d_in, const int* in_sizes, int n_in,
                              void* d_out, int out_size, void* d_ws, size_t ws_size,
                              hipStream_t stream) {
    const float* x     = (const float*)d_in[0];
    const int*   ei    = (const int*)d_in[1];
    const int*   batch = (const int*)d_in[2];
    const float* W_gcn = (const float*)d_in[3];
    const float* b_gcn = (const float*)d_in[4];
    const float* w_ih  = (const float*)d_in[5];
    const float* w_hh  = (const float*)d_in[6];
    const float* b_ih  = (const float*)d_in[7];
    const float* b_hh  = (const float*)d_in[8];
    const float* W_fc  = (const float*)d_in[9];
    const float* b_fc  = (const float*)d_in[10];
    float* out = (float*)d_out;

    char* ws = (char*)d_ws;
    __half* yh    = (__half*)ws;                                   // 25.6 MB
    __half* wt16  = (__half*)(ws + (size_t)NNODES * DIM * 2);      // 32 KB
    unsigned* partial = (unsigned*)(ws + (size_t)NNODES * DIM * 2 + (1 << 16));  // 12.8 MB
    float*  dinv  = (float*)(ws + (size_t)NNODES * DIM * 4);       // 400 KB
    float*  sums  = dinv + 100096;
    float*  xg    = sums + NG * DIM;
    int*    deg   = (int*)(xg + NG * GATE);
    int*    row_ptr = deg + 100096;
    int*    cursor  = row_ptr + 100096;
    int*    adj     = cursor + 100096;      // 6.4 MB
    int*    start   = adj + NEDGES;
    int*    bsum    = start + 128;
    __half* whh16   = (__half*)(bsum + 128);  // 128 KB fp16 LSTM weights (row-major)

    hipMemsetAsync(sums, 0, NG * DIM * sizeof(float), stream);

    bool hist_ok = hipFuncSetAttribute((const void*)k_deghist,
                                       hipFuncAttributeMaxDynamicSharedMemorySize,
                                       HSMEM) == hipSuccess;
    if (hist_ok) {
        k_deghist<<<HG, 1024, HSMEM, stream>>>(ei, partial);
        k_degred<<<(NNODES / 4 + 255) / 256, 256, 0, stream>>>(partial, deg, dinv);
    } else {
        hipMemsetAsync(deg, 0, NNODES * sizeof(int), stream);
        k_deg<<<(NEDGES + 255) / 256, 256, 0, stream>>>(ei, deg);
        k_dinv<<<(NNODES + 255) / 256, 256, 0, stream>>>(deg, dinv);
    }
    k_scan1<<<SCAN_NB, 1024, 0, stream>>>(deg, row_ptr, bsum);
    k_scan2<<<1, 128, 0, stream>>>(bsum, row_ptr, batch, start);
    k_scan3<<<SCAN_NB, 1024, 0, stream>>>(row_ptr, bsum, cursor);
    for (int p = 0; p < FILL_NPASS; ++p)
        k_fillb<<<(NEDGES + 255) / 256, 256, 0, stream>>>(ei, cursor, adj, p * BUCKET);
    k_wprep<<<(GATE * DIM + DIM * DIM + 255) / 256, 256, 0, stream>>>(W_gcn, w_hh, wt16, whh16);
    k_gemmm<<<(NNODES + 63) / 64, 256, 0, stream>>>(x, wt16, dinv, yh);
    k_gpool<<<NNODES / 16, 256, 0, stream>>>(row_ptr, adj, (const float4*)yh, dinv, b_gcn, batch, sums);
    k_xgate<<<NG, 512, 0, stream>>>(sums, start, w_ih, b_ih, b_hh, xg);

    bool lds_ok = hipFuncSetAttribute((const void*)k_lstm2<1>,
                                      hipFuncAttributeMaxDynamicSharedMemorySize,
                                      SMEM_TOTAL) == hipSuccess;
    if (lds_ok)
        k_lstm2<1><<<1, 512, SMEM_TOTAL, stream>>>(xg, whh16, W_fc, b_fc, out);
    else
        k_lstm2<0><<<1, 512, SMEM_AUX, stream>>>(xg, whh16, W_fc, b_fc, out);
}

// Round 12
// 283.613 us; speedup vs baseline: 1.7063x; 1.0942x over previous
//
#include <hip/hip_runtime.h>
#include <hip/hip_fp16.h>
#include <math.h>

#if __has_builtin(__builtin_amdgcn_cvt_pk_f32_fp8) && __has_builtin(__builtin_amdgcn_cvt_pk_fp8_f32)
#define HAS_FP8_CVT 1
#else
#include <hip/hip_fp8.h>
#endif

#define NNODES 100000
#define NEDGES 1600000
#define DIM 128
#define NG 64
#define GATE 512
#define SCAN_NB 98  // ceil(NNODES / 1024)
#define FILL_NPASS 4
#define BUCKET ((NNODES + FILL_NPASS - 1) / FILL_NPASS)  // 25000

// degree histogram
#define HG 128           // partial-histogram blocks
#define HW 25024         // u32 words per partial (4 packed u8 cols each)
#define HSMEM (HW * 4)   // 100096 B dynamic LDS

// k_lstm2 dynamic LDS layout
#define SMEM_W   131072                       // 512 rows x 16 chunks x 16 B (fp16, swizzled)
#define SMEM_AUX (256 + 2048 + 16384)         // h2h + gates + hsh
#define SMEM_TOTAL (SMEM_W + SMEM_AUX)        // 149760 <= 160K/CU

typedef _Float16 f16x2 __attribute__((ext_vector_type(2)));
typedef _Float16 half8_t __attribute__((ext_vector_type(8)));
typedef float f32x4 __attribute__((ext_vector_type(4)));
typedef float f32x2_t __attribute__((ext_vector_type(2)));

__device__ __forceinline__ f16x2 f2h2cast(float f) {
    union U { float f; f16x2 h; } u; u.f = f; return u.h;
}
__device__ __forceinline__ float fdot2f(f16x2 a, f16x2 b, float c) {
#if __has_builtin(__builtin_amdgcn_fdot2)
    return __builtin_amdgcn_fdot2(a, b, c, false);
#else
    return c + (float)a[0] * (float)b[0] + (float)a[1] * (float)b[1];
#endif
}

// fp8 e4m3 HW converters (encode/decode self-consistent on gfx950)
__device__ __forceinline__ unsigned char f32_to_fp8(float v) {
#ifdef HAS_FP8_CVT
    return (unsigned char)(__builtin_amdgcn_cvt_pk_fp8_f32(v, v, 0, false) & 0xFF);
#else
    __hip_fp8_e4m3 h(v); return h.__x;
#endif
}
__device__ __forceinline__ void fp8x4_acc(unsigned w, float* acc) {
#ifdef HAS_FP8_CVT
    f32x2_t lo = __builtin_amdgcn_cvt_pk_f32_fp8((int)w, false);
    f32x2_t hi = __builtin_amdgcn_cvt_pk_f32_fp8((int)w, true);
    acc[0] += lo[0]; acc[1] += lo[1]; acc[2] += hi[0]; acc[3] += hi[1];
#else
    __hip_fp8_e4m3 h;
#pragma unroll
    for (int q = 0; q < 4; ++q) { h.__x = (w >> (8 * q)) & 0xFF; acc[q] += (float)h; }
#endif
}

// fast sigmoid/tanh: v_exp_f32 + v_rcp_f32 (absmax headroom is ~100x)
__device__ __forceinline__ float sigf(float x) {
    return __builtin_amdgcn_rcpf(1.0f + __expf(-x));
}
__device__ __forceinline__ float tanhfast(float x) {
    float e = __expf(2.0f * x);
    return 1.0f - 2.0f * __builtin_amdgcn_rcpf(e + 1.0f);
}

// ---- degree: per-block LDS u8-packed histogram, NO global atomics ----
__global__ __launch_bounds__(1024) void k_deghist(const int* __restrict__ ei, unsigned* __restrict__ partial) {
    extern __shared__ unsigned hist[];  // HW words
    int tid = threadIdx.x;
    for (int i = tid; i < HW; i += 1024) hist[i] = 0u;
    __syncthreads();
    int e0 = blockIdx.x * (NEDGES / HG);
    int e1 = e0 + (NEDGES / HG);
    for (int e = e0 + tid; e < e1; e += 1024) {
        int col = ei[NEDGES + e];
        atomicAdd(&hist[col >> 2], 1u << ((col & 3) * 8));
    }
    __syncthreads();
    unsigned* dst = partial + (size_t)blockIdx.x * HW;
    for (int i = tid; i < HW; i += 1024) dst[i] = hist[i];
}

// fallback if 100KB dynamic LDS unavailable: plain atomic count
__global__ __launch_bounds__(256) void k_deg(const int* __restrict__ ei, int* __restrict__ deg) {
    int e = blockIdx.x * 256 + threadIdx.x;
    if (e < NEDGES) atomicAdd(&deg[ei[NEDGES + e]], 1);
}

// sum HG partials, emit deg + dinv
__global__ __launch_bounds__(256) void k_degred(const unsigned* __restrict__ partial, int* __restrict__ deg,
                                                float* __restrict__ dinv) {
    int w = blockIdx.x * 256 + threadIdx.x;  // packed word = 4 nodes
    if (w >= NNODES / 4) return;
    unsigned s = 0;
    for (int b = 0; b < HG; ++b) s += partial[(size_t)b * HW + w];
    int4 d;
    d.x = s & 255; d.y = (s >> 8) & 255; d.z = (s >> 16) & 255; d.w = (int)(s >> 24);
    ((int4*)deg)[w] = d;
    float4 dv;
    dv.x = rsqrtf((float)d.x + 1.f);
    dv.y = rsqrtf((float)d.y + 1.f);
    dv.z = rsqrtf((float)d.z + 1.f);
    dv.w = rsqrtf((float)d.w + 1.f);
    ((float4*)dinv)[w] = dv;
}

// dinv for the atomic fallback path
__global__ __launch_bounds__(256) void k_dinv(const int* __restrict__ deg, float* __restrict__ dinv) {
    int n = blockIdx.x * 256 + threadIdx.x;
    if (n < NNODES) dinv[n] = rsqrtf((float)deg[n] + 1.0f);
}

// stage 1: per-block exclusive scan of deg; block sums out
__global__ __launch_bounds__(1024) void k_scan1(const int* __restrict__ deg, int* __restrict__ row_ptr,
                                                int* __restrict__ bsum) {
    __shared__ int ls[1024];
    int tid = threadIdx.x;
    int n = blockIdx.x * 1024 + tid;
    int v = (n < NNODES) ? deg[n] : 0;
    ls[tid] = v;
    __syncthreads();
    for (int off = 1; off < 1024; off <<= 1) {
        int t = (tid >= off) ? ls[tid - off] : 0;
        __syncthreads();
        ls[tid] += t;
        __syncthreads();
    }
    if (n < NNODES) row_ptr[n] = ls[tid] - v;  // exclusive within block
    if (tid == 1023) bsum[blockIdx.x] = ls[1023];
}

// stage 2: exclusive scan of block sums + graph segment bounds (batch sorted)
__global__ __launch_bounds__(128) void k_scan2(int* __restrict__ bsum, int* __restrict__ row_ptr,
                                               const int* __restrict__ batch, int* __restrict__ start) {
    __shared__ int ls[128];
    int tid = threadIdx.x;
    int v = (tid < SCAN_NB) ? bsum[tid] : 0;
    ls[tid] = v;
    __syncthreads();
    for (int off = 1; off < 128; off <<= 1) {
        int t = (tid >= off) ? ls[tid - off] : 0;
        __syncthreads();
        ls[tid] += t;
        __syncthreads();
    }
    if (tid < SCAN_NB) bsum[tid] = ls[tid] - v;  // exclusive block offsets
    if (tid == 127) row_ptr[NNODES] = ls[127];
    // graph bounds via binary search
    if (tid <= NG) {
        int lo = 0, hi = NNODES;
        while (lo < hi) {
            int mid = (lo + hi) >> 1;
            if (batch[mid] < tid) lo = mid + 1; else hi = mid;
        }
        start[tid] = lo;
    }
}

// stage 3: add block offsets; init cursor = row_ptr
__global__ __launch_bounds__(1024) void k_scan3(int* __restrict__ row_ptr, const int* __restrict__ bsum,
                                                int* __restrict__ cursor) {
    int n = blockIdx.x * 1024 + threadIdx.x;
    if (n < NNODES) {
        int rp = row_ptr[n] + bsum[blockIdx.x];
        row_ptr[n] = rp;
        cursor[n] = rp;
    }
}

// adj[cursor[col]++] = row, cols in [b0, b0+BUCKET): temporal bucketing
__global__ __launch_bounds__(256) void k_fillb(const int* __restrict__ ei, int* __restrict__ cursor,
                                               int* __restrict__ adj, int b0) {
    int e = blockIdx.x * 256 + threadIdx.x;
    if (e < NEDGES) {
        int col = ei[NEDGES + e];
        if (col >= b0 && col < b0 + BUCKET) {
            int row = ei[e];
            int pos = atomicAdd(&cursor[col], 1);
            adj[pos] = row;
        }
    }
}

// fused weight prep: w_hh -> fp16 row-major; W_gcn -> fp16 transposed [d][k]
__global__ __launch_bounds__(256) void k_wprep(const float* __restrict__ W_gcn, const float* __restrict__ w_hh,
                                               __half* __restrict__ Wt, __half* __restrict__ whh16) {
    int t = blockIdx.x * 256 + threadIdx.x;
    if (t < GATE * DIM) {
        whh16[t] = __float2half(w_hh[t]);
    } else {
        int idx = t - GATE * DIM;
        if (idx < DIM * DIM) {
            int d = idx >> 7, k = idx & 127;
            Wt[idx] = __float2half(W_gcn[k * DIM + d]);
        }
    }
}

// y[n] = (x[n] @ W) * dinv[n] via v_mfma_f32_16x16x32_f16, fp8 e4m3 out.
__global__ __launch_bounds__(256) void k_gemmm(const float* __restrict__ x, const __half* __restrict__ Wt,
                                               const float* __restrict__ dinv, unsigned char* __restrict__ yf8) {
    int tid = threadIdx.x;
    int wt = tid >> 6, lane = tid & 63;
    int lr = lane & 15, kgrp = lane >> 4;
    int rb = blockIdx.x * 64 + wt * 16;

    int rowA = rb + lr;
    if (rowA >= NNODES) rowA = NNODES - 1;
    const float4* x4 = (const float4*)x;

    f32x4 acc[8];
#pragma unroll
    for (int ct = 0; ct < 8; ++ct) acc[ct] = (f32x4){0.f, 0.f, 0.f, 0.f};

#pragma unroll
    for (int c = 0; c < 4; ++c) {
        int kb = c * 32 + kgrp * 8;
        float4 v0 = x4[(size_t)rowA * 32 + (kb >> 2)];
        float4 v1 = x4[(size_t)rowA * 32 + (kb >> 2) + 1];
        half8_t a;
        a[0] = (_Float16)v0.x; a[1] = (_Float16)v0.y; a[2] = (_Float16)v0.z; a[3] = (_Float16)v0.w;
        a[4] = (_Float16)v1.x; a[5] = (_Float16)v1.y; a[6] = (_Float16)v1.z; a[7] = (_Float16)v1.w;
#pragma unroll
        for (int ct = 0; ct < 8; ++ct) {
            int col = ct * 16 + lr;
            half8_t b = *(const half8_t*)(Wt + (size_t)col * DIM + kb);
            acc[ct] = __builtin_amdgcn_mfma_f32_16x16x32_f16(a, b, acc[ct], 0, 0, 0);
        }
    }

    int rowbase = rb + kgrp * 4;
    float dv[4];
    bool ok[4];
#pragma unroll
    for (int r = 0; r < 4; ++r) {
        int row = rowbase + r;
        ok[r] = row < NNODES;
        dv[r] = ok[r] ? dinv[row] : 0.f;
    }
#pragma unroll
    for (int ct = 0; ct < 8; ++ct) {
#pragma unroll
        for (int r = 0; r < 4; ++r) {
            if (ok[r])
                yf8[(size_t)(rowbase + r) * DIM + ct * 16 + lr] = f32_to_fp8(acc[ct][r] * dv[r]);
        }
    }
}

// Fused gather + ReLU + mean-pool partial sums (16 nodes/block, exact grid).
// Y rows are 128 B fp8: 16 lanes x uint2 (8 dims each); 4-deep neighbor unroll
// for memory-level parallelism; f32 accumulate; HW cvt_pk_f32_fp8 unpack.
__global__ __launch_bounds__(256) void k_gpool(const int* __restrict__ row_ptr, const int* __restrict__ adj,
                                               const uint2* __restrict__ Y, const float* __restrict__ dinv,
                                               const float* __restrict__ bias, const int* __restrict__ batch,
                                               float* __restrict__ sums) {
    __shared__ float red[16][132];  // +4 pad
    __shared__ int gid[16];
    int tid = threadIdx.x;
    int sl = tid >> 4;   // node slot
    int l = tid & 15;    // 8B chunk (dims 8l..8l+7)
    int n = blockIdx.x * 16 + sl;

    int s = row_ptr[n], e = row_ptr[n + 1];
    float acc[8];
#pragma unroll
    for (int q = 0; q < 8; ++q) acc[q] = 0.f;
    {
        uint2 v = Y[(size_t)n * 16 + l];  // self-loop term
        fp8x4_acc(v.x, acc);
        fp8x4_acc(v.y, acc + 4);
    }
    int i = s;
    for (; i + 3 < e; i += 4) {
        int r0 = adj[i], r1 = adj[i + 1], r2 = adj[i + 2], r3 = adj[i + 3];
        uint2 a0 = Y[(size_t)r0 * 16 + l];
        uint2 a1 = Y[(size_t)r1 * 16 + l];
        uint2 a2 = Y[(size_t)r2 * 16 + l];
        uint2 a3 = Y[(size_t)r3 * 16 + l];
        fp8x4_acc(a0.x, acc); fp8x4_acc(a0.y, acc + 4);
        fp8x4_acc(a1.x, acc); fp8x4_acc(a1.y, acc + 4);
        fp8x4_acc(a2.x, acc); fp8x4_acc(a2.y, acc + 4);
        fp8x4_acc(a3.x, acc); fp8x4_acc(a3.y, acc + 4);
    }
    for (; i < e; ++i) {
        uint2 a0 = Y[(size_t)adj[i] * 16 + l];
        fp8x4_acc(a0.x, acc); fp8x4_acc(a0.y, acc + 4);
    }

    float dv = dinv[n];
#pragma unroll
    for (int q = 0; q < 8; ++q) {
        float v = dv * acc[q] + bias[l * 8 + q];
        red[sl][l * 8 + q] = fmaxf(v, 0.f);
    }
    if (l == 0) gid[sl] = batch[n];
    __syncthreads();

    if (tid < DIM) {
        int d = tid;
        float a = 0.f;
        int g = gid[0];
        for (int s2 = 0; s2 < 16; ++s2) {
            int gs = gid[s2];
            if (gs != g) {
                if (a != 0.f) atomicAdd(&sums[g * DIM + d], a);
                a = 0.f; g = gs;
            }
            a += red[s2][d];
        }
        if (a != 0.f) atomicAdd(&sums[g * DIM + d], a);
    }
}

// xg[t][j] = b_ih[j] + b_hh[j] + pooled[t] . w_ih[j]
__global__ __launch_bounds__(512) void k_xgate(const float* __restrict__ sums, const int* __restrict__ start,
                                               const float* __restrict__ w_ih, const float* __restrict__ b_ih,
                                               const float* __restrict__ b_hh, float* __restrict__ xg) {
    __shared__ float4 p4[DIM / 4];
    int t = blockIdx.x, j = threadIdx.x;
    if (j < DIM) {
        int c = start[t + 1] - start[t];
        float inv = 1.0f / fmaxf((float)c, 1.0f);
        ((float*)p4)[j] = sums[t * DIM + j] * inv;
    }
    __syncthreads();
    const float4* w4 = (const float4*)(w_ih + (size_t)j * DIM);
    float acc = b_ih[j] + b_hh[j];
#pragma unroll
    for (int kk = 0; kk < 32; ++kk) {
        float4 w = w4[kk];
        float4 p = p4[kk];
        acc += w.x * p.x + w.y * p.y + w.z * p.z + w.w * p.w;
    }
    xg[t * GATE + j] = acc;
}

// Sequential LSTM + FC. fp16 weights in 128 KB LDS, ds_read_b128 with XOR
// chunk swizzle (R10: 77 -> ~40 us; b32 was issue-bound at 512 instr/step).
template <int LDSW>
__global__ __launch_bounds__(512) void k_lstm2(const float* __restrict__ xg, const __half* __restrict__ whh16,
                                               const float* __restrict__ Wfc, const float* __restrict__ bfc,
                                               float* __restrict__ out) {
    extern __shared__ char smem[];
    half8_t* w8L = (half8_t*)smem;                     // LDSW only
    char* aux = LDSW ? (smem + SMEM_W) : smem;
    __half* h2h = (__half*)aux;                        // 128 halves
    float* gates = (float*)(aux + 256);                // 512 f32
    __half* hsh = (__half*)(aux + 256 + 2048);         // 64*128 halves
    int j = threadIdx.x;
    int sw = j & 15;

    if (LDSW) {
#pragma unroll
        for (int c = 0; c < 16; ++c) {
            half8_t g = *(const half8_t*)(whh16 + (size_t)j * DIM + 8 * c);
            w8L[j * 16 + (c ^ sw)] = g;
        }
    }
    if (j < DIM) h2h[j] = __float2half(0.f);
    float c = 0.f;
    float xcur = xg[j];
    __syncthreads();

    const half8_t* wrow = LDSW ? (const half8_t*)w8L : (const half8_t*)whh16;
    const float4* h4 = (const float4*)h2h;
    for (int t = 0; t < NG; ++t) {
        float xnext = (t + 1 < NG) ? xg[(t + 1) * GATE + j] : 0.f;
        float acc = xcur;
#pragma unroll
        for (int cc = 0; cc < 16; ++cc) {
            int idx = LDSW ? (j * 16 + (cc ^ sw)) : (j * 16 + cc);
            union { half8_t v; f16x2 p[4]; } w;
            w.v = wrow[idx];
            float4 hr = h4[cc];  // broadcast: halves 8cc..8cc+7
            acc = fdot2f(w.p[0], f2h2cast(hr.x), acc);
            acc = fdot2f(w.p[1], f2h2cast(hr.y), acc);
            acc = fdot2f(w.p[2], f2h2cast(hr.z), acc);
            acc = fdot2f(w.p[3], f2h2cast(hr.w), acc);
        }
        gates[j] = acc;
        __syncthreads();
        if (j < DIM) {
            float gi = gates[j], gf = gates[DIM + j], gg = gates[2 * DIM + j], go = gates[3 * DIM + j];
            c = sigf(gf) * c + sigf(gi) * tanhfast(gg);
            float hn = sigf(go) * tanhfast(c);
            h2h[j] = __float2half(hn);
            hsh[t * DIM + j] = __float2half(hn);
        }
        xcur = xnext;
        __syncthreads();
    }

    // FC: out[t][cls] = b_fc[cls] + hs[t] . W_fc[cls]
    for (int o = j; o < NG * 10; o += 512) {
        int t = o / 10, cls = o - t * 10;
        const __half2* hv = (const __half2*)(hsh + t * DIM);
        float acc = bfc[cls];
#pragma unroll
        for (int kk = 0; kk < 64; ++kk) {
            float2 hf = __half22float2(hv[kk]);
            acc += hf.x * Wfc[cls * DIM + 2 * kk] + hf.y * Wfc[cls * DIM + 2 * kk + 1];
        }
        out[o] = acc;
    }
}

extern "C" void kernel_launch(void* const* d_in, const int* in_sizes, int n_in,
                              void* d_out, int out_size, void* d_ws, size_t ws_size,
                              hipStream_t stream) {
    const float* x     = (const float*)d_in[0];
    const int*   ei    = (const int*)d_in[1];
    const int*   batch = (const int*)d_in[2];
    const float* W_gcn = (const float*)d_in[3];
    const float* b_gcn = (const float*)d_in[4];
    const float* w_ih  = (const float*)d_in[5];
    const float* w_hh  = (const float*)d_in[6];
    const float* b_ih  = (const float*)d_in[7];
    const float* b_hh  = (const float*)d_in[8];
    const float* W_fc  = (const float*)d_in[9];
    const float* b_fc  = (const float*)d_in[10];
    float* out = (float*)d_out;

    char* ws = (char*)d_ws;
    unsigned char* yf8 = (unsigned char*)ws;                       // 12.8 MB (fp8)
    __half* wt16  = (__half*)(ws + (size_t)NNODES * DIM * 2);      // 32 KB
    unsigned* partial = (unsigned*)(ws + (size_t)NNODES * DIM * 2 + (1 << 16));  // 12.8 MB
    float*  dinv  = (float*)(ws + (size_t)NNODES * DIM * 4);       // 400 KB
    float*  sums  = dinv + 100096;
    float*  xg    = sums + NG * DIM;
    int*    deg   = (int*)(xg + NG * GATE);
    int*    row_ptr = deg + 100096;
    int*    cursor  = row_ptr + 100096;
    int*    adj     = cursor + 100096;      // 6.4 MB
    int*    start   = adj + NEDGES;
    int*    bsum    = start + 128;
    __half* whh16   = (__half*)(bsum + 128);  // 128 KB fp16 LSTM weights (row-major)

    hipMemsetAsync(sums, 0, NG * DIM * sizeof(float), stream);

    bool hist_ok = hipFuncSetAttribute((const void*)k_deghist,
                                       hipFuncAttributeMaxDynamicSharedMemorySize,
                                       HSMEM) == hipSuccess;
    if (hist_ok) {
        k_deghist<<<HG, 1024, HSMEM, stream>>>(ei, partial);
        k_degred<<<(NNODES / 4 + 255) / 256, 256, 0, stream>>>(partial, deg, dinv);
    } else {
        hipMemsetAsync(deg, 0, NNODES * sizeof(int), stream);
        k_deg<<<(NEDGES + 255) / 256, 256, 0, stream>>>(ei, deg);
        k_dinv<<<(NNODES + 255) / 256, 256, 0, stream>>>(deg, dinv);
    }
    k_scan1<<<SCAN_NB, 1024, 0, stream>>>(deg, row_ptr, bsum);
    k_scan2<<<1, 128, 0, stream>>>(bsum, row_ptr, batch, start);
    k_scan3<<<SCAN_NB, 1024, 0, stream>>>(row_ptr, bsum, cursor);
    for (int p = 0; p < FILL_NPASS; ++p)
        k_fillb<<<(NEDGES + 255) / 256, 256, 0, stream>>>(ei, cursor, adj, p * BUCKET);
    k_wprep<<<(GATE * DIM + DIM * DIM + 255) / 256, 256, 0, stream>>>(W_gcn, w_hh, wt16, whh16);
    k_gemmm<<<(NNODES + 63) / 64, 256, 0, stream>>>(x, wt16, dinv, yf8);
    k_gpool<<<NNODES / 16, 256, 0, stream>>>(row_ptr, adj, (const uint2*)yf8, dinv, b_gcn, batch, sums);
    k_xgate<<<NG, 512, 0, stream>>>(sums, start, w_ih, b_ih, b_hh, xg);

    bool lds_ok = hipFuncSetAttribute((const void*)k_lstm2<1>,
                                      hipFuncAttributeMaxDynamicSharedMemorySize,
                                      SMEM_TOTAL) == hipSuccess;
    if (lds_ok)
        k_lstm2<1><<<1, 512, SMEM_TOTAL, stream>>>(xg, whh16, W_fc, b_fc, out);
    else
        k_lstm2<0><<<1, 512, SMEM_AUX, stream>>>(xg, whh16, W_fc, b_fc, out);
}

// Round 13
// 236.166 us; speedup vs baseline: 2.0492x; 1.2009x over previous
//
#include <hip/hip_runtime.h>
#include <hip/hip_fp16.h>
#include <math.h>

#if __has_builtin(__builtin_amdgcn_cvt_pk_f32_fp8) && __has_builtin(__builtin_amdgcn_cvt_pk_fp8_f32)
#define HAS_FP8_CVT 1
#else
#include <hip/hip_fp8.h>
#endif

#define NNODES 100000
#define NEDGES 1600000
#define DIM 128
#define NG 64
#define GATE 512
#define SCAN_NB 98  // ceil(NNODES / 1024)
#define FILL_NPASS 4
#define BUCKET ((NNODES + FILL_NPASS - 1) / FILL_NPASS)  // 25000

// degree histogram / counting-sort offsets
#define HG 128           // edge chunks (12500 edges each)
#define HW 25024         // u32 words per partial (4 packed u8 cols each)
#define HSMEM (HW * 4)   // 100096 B dynamic LDS for k_deghist

typedef _Float16 half8_t __attribute__((ext_vector_type(8)));
typedef float f32x4 __attribute__((ext_vector_type(4)));
typedef float f32x2_t __attribute__((ext_vector_type(2)));

// fp8 e4m3 HW converters (encode/decode self-consistent on gfx950)
__device__ __forceinline__ unsigned char f32_to_fp8(float v) {
#ifdef HAS_FP8_CVT
    return (unsigned char)(__builtin_amdgcn_cvt_pk_fp8_f32(v, v, 0, false) & 0xFF);
#else
    __hip_fp8_e4m3 h(v); return h.__x;
#endif
}
__device__ __forceinline__ void fp8x4_acc(unsigned w, float* acc) {
#ifdef HAS_FP8_CVT
    f32x2_t lo = __builtin_amdgcn_cvt_pk_f32_fp8((int)w, false);
    f32x2_t hi = __builtin_amdgcn_cvt_pk_f32_fp8((int)w, true);
    acc[0] += lo[0]; acc[1] += lo[1]; acc[2] += hi[0]; acc[3] += hi[1];
#else
    __hip_fp8_e4m3 h;
#pragma unroll
    for (int q = 0; q < 4; ++q) { h.__x = (w >> (8 * q)) & 0xFF; acc[q] += (float)h; }
#endif
}

// fast sigmoid/tanh: v_exp_f32 + v_rcp_f32 (absmax headroom is ~100x)
__device__ __forceinline__ float sigf(float x) {
    return __builtin_amdgcn_rcpf(1.0f + __expf(-x));
}
__device__ __forceinline__ float tanhfast(float x) {
    float e = __expf(2.0f * x);
    return 1.0f - 2.0f * __builtin_amdgcn_rcpf(e + 1.0f);
}

// ---- degree: per-edge-chunk LDS u8-packed histogram, NO global atomics ----
__global__ __launch_bounds__(1024) void k_deghist(const int* __restrict__ ei, unsigned* __restrict__ partial) {
    extern __shared__ unsigned hist[];  // HW words
    int tid = threadIdx.x;
    for (int i = tid; i < HW; i += 1024) hist[i] = 0u;
    __syncthreads();
    int e0 = blockIdx.x * (NEDGES / HG);
    int e1 = e0 + (NEDGES / HG);
    for (int e = e0 + tid; e < e1; e += 1024) {
        int col = ei[NEDGES + e];
        atomicAdd(&hist[col >> 2], 1u << ((col & 3) * 8));
    }
    __syncthreads();
    unsigned* dst = partial + (size_t)blockIdx.x * HW;
    for (int i = tid; i < HW; i += 1024) dst[i] = hist[i];
}

// fallback if 100KB dynamic LDS unavailable: plain atomic count
__global__ __launch_bounds__(256) void k_deg(const int* __restrict__ ei, int* __restrict__ deg) {
    int e = blockIdx.x * 256 + threadIdx.x;
    if (e < NEDGES) atomicAdd(&deg[ei[NEDGES + e]], 1);
}

// sum HG partials -> deg + dinv, and emit per-chunk exclusive prefix pre8
// (packed u8; per-col total = deg <= ~60 so every prefix fits a byte)
__global__ __launch_bounds__(256) void k_degred2(const unsigned* __restrict__ partial, unsigned* __restrict__ pre8,
                                                 int* __restrict__ deg, float* __restrict__ dinv) {
    int w = blockIdx.x * 256 + threadIdx.x;  // packed word = 4 cols
    if (w >= NNODES / 4) return;
    unsigned s = 0;
    for (int b = 0; b < HG; ++b) {
        pre8[(size_t)b * HW + w] = s;        // exclusive prefix before chunk b
        s += partial[(size_t)b * HW + w];
    }
    int4 d;
    d.x = s & 255; d.y = (s >> 8) & 255; d.z = (s >> 16) & 255; d.w = (int)(s >> 24);
    ((int4*)deg)[w] = d;
    float4 dv;
    dv.x = rsqrtf((float)d.x + 1.f);
    dv.y = rsqrtf((float)d.y + 1.f);
    dv.z = rsqrtf((float)d.z + 1.f);
    dv.w = rsqrtf((float)d.w + 1.f);
    ((float4*)dinv)[w] = dv;
}

// dinv for the atomic fallback path
__global__ __launch_bounds__(256) void k_dinv(const int* __restrict__ deg, float* __restrict__ dinv) {
    int n = blockIdx.x * 256 + threadIdx.x;
    if (n < NNODES) dinv[n] = rsqrtf((float)deg[n] + 1.0f);
}

// stage 1: per-block exclusive scan of deg; block sums out
__global__ __launch_bounds__(1024) void k_scan1(const int* __restrict__ deg, int* __restrict__ row_ptr,
                                                int* __restrict__ bsum) {
    __shared__ int ls[1024];
    int tid = threadIdx.x;
    int n = blockIdx.x * 1024 + tid;
    int v = (n < NNODES) ? deg[n] : 0;
    ls[tid] = v;
    __syncthreads();
    for (int off = 1; off < 1024; off <<= 1) {
        int t = (tid >= off) ? ls[tid - off] : 0;
        __syncthreads();
        ls[tid] += t;
        __syncthreads();
    }
    if (n < NNODES) row_ptr[n] = ls[tid] - v;  // exclusive within block
    if (tid == 1023) bsum[blockIdx.x] = ls[1023];
}

// stage 2: exclusive scan of block sums + graph segment bounds (batch sorted)
__global__ __launch_bounds__(128) void k_scan2(int* __restrict__ bsum, int* __restrict__ row_ptr,
                                               const int* __restrict__ batch, int* __restrict__ start) {
    __shared__ int ls[128];
    int tid = threadIdx.x;
    int v = (tid < SCAN_NB) ? bsum[tid] : 0;
    ls[tid] = v;
    __syncthreads();
    for (int off = 1; off < 128; off <<= 1) {
        int t = (tid >= off) ? ls[tid - off] : 0;
        __syncthreads();
        ls[tid] += t;
        __syncthreads();
    }
    if (tid < SCAN_NB) bsum[tid] = ls[tid] - v;  // exclusive block offsets
    if (tid == 127) row_ptr[NNODES] = ls[127];
    if (tid <= NG) {
        int lo = 0, hi = NNODES;
        while (lo < hi) {
            int mid = (lo + hi) >> 1;
            if (batch[mid] < tid) lo = mid + 1; else hi = mid;
        }
        start[tid] = lo;
    }
}

// stage 3: add block offsets; init cursor = row_ptr (cursor used by fallback fill only)
__global__ __launch_bounds__(1024) void k_scan3(int* __restrict__ row_ptr, const int* __restrict__ bsum,
                                                int* __restrict__ cursor) {
    int n = blockIdx.x * 1024 + threadIdx.x;
    if (n < NNODES) {
        int rp = row_ptr[n] + bsum[blockIdx.x];
        row_ptr[n] = rp;
        cursor[n] = rp;
    }
}

// Atomic-free CSR fill: block b owns edge chunk b (order matches k_deghist);
// slot = row_ptr[col] + pre8[b][col] + local, local from the RETURNED OLD
// value of a packed-u8 LDS atomicAdd. Col-bucketed (4 passes) so adj writes
// stay in a 1.6 MB window. Zero global atomics.
__global__ __launch_bounds__(1024) void k_fill2(const int* __restrict__ ei, const int* __restrict__ row_ptr,
                                                const unsigned* __restrict__ pre8, int* __restrict__ adj, int b0) {
    __shared__ unsigned lh[BUCKET / 4];  // 25 KB
    int tid = threadIdx.x;
    for (int i = tid; i < BUCKET / 4; i += 1024) lh[i] = 0u;
    __syncthreads();
    const unsigned* myPre = pre8 + (size_t)blockIdx.x * HW;
    int e0 = blockIdx.x * (NEDGES / HG);
    int e1 = e0 + (NEDGES / HG);
    for (int e = e0 + tid; e < e1; e += 1024) {
        int col = ei[NEDGES + e];
        if (col >= b0 && col < b0 + BUCKET) {
            int row = ei[e];
            int lc = col - b0;
            unsigned old = atomicAdd(&lh[lc >> 2], 1u << ((lc & 3) * 8));
            int local = (old >> ((lc & 3) * 8)) & 0xFF;
            int base = row_ptr[col] + (int)((myPre[col >> 2] >> ((col & 3) * 8)) & 0xFF);
            adj[base + local] = row;
        }
    }
}

// fallback: cursor-based fill with temporal bucketing
__global__ __launch_bounds__(256) void k_fillb(const int* __restrict__ ei, int* __restrict__ cursor,
                                               int* __restrict__ adj, int b0) {
    int e = blockIdx.x * 256 + threadIdx.x;
    if (e < NEDGES) {
        int col = ei[NEDGES + e];
        if (col >= b0 && col < b0 + BUCKET) {
            int row = ei[e];
            int pos = atomicAdd(&cursor[col], 1);
            adj[pos] = row;
        }
    }
}

// fused weight prep: w_hh -> fp16 row-major; W_gcn -> fp16 transposed [d][k]
__global__ __launch_bounds__(256) void k_wprep(const float* __restrict__ W_gcn, const float* __restrict__ w_hh,
                                               __half* __restrict__ Wt, __half* __restrict__ whh16) {
    int t = blockIdx.x * 256 + threadIdx.x;
    if (t < GATE * DIM) {
        whh16[t] = __float2half(w_hh[t]);
    } else {
        int idx = t - GATE * DIM;
        if (idx < DIM * DIM) {
            int d = idx >> 7, k = idx & 127;
            Wt[idx] = __float2half(W_gcn[k * DIM + d]);
        }
    }
}

// y[n] = (x[n] @ W) * dinv[n] via v_mfma_f32_16x16x32_f16, fp8 e4m3 out.
__global__ __launch_bounds__(256) void k_gemmm(const float* __restrict__ x, const __half* __restrict__ Wt,
                                               const float* __restrict__ dinv, unsigned char* __restrict__ yf8) {
    int tid = threadIdx.x;
    int wt = tid >> 6, lane = tid & 63;
    int lr = lane & 15, kgrp = lane >> 4;
    int rb = blockIdx.x * 64 + wt * 16;

    int rowA = rb + lr;
    if (rowA >= NNODES) rowA = NNODES - 1;
    const float4* x4 = (const float4*)x;

    f32x4 acc[8];
#pragma unroll
    for (int ct = 0; ct < 8; ++ct) acc[ct] = (f32x4){0.f, 0.f, 0.f, 0.f};

#pragma unroll
    for (int c = 0; c < 4; ++c) {
        int kb = c * 32 + kgrp * 8;
        float4 v0 = x4[(size_t)rowA * 32 + (kb >> 2)];
        float4 v1 = x4[(size_t)rowA * 32 + (kb >> 2) + 1];
        half8_t a;
        a[0] = (_Float16)v0.x; a[1] = (_Float16)v0.y; a[2] = (_Float16)v0.z; a[3] = (_Float16)v0.w;
        a[4] = (_Float16)v1.x; a[5] = (_Float16)v1.y; a[6] = (_Float16)v1.z; a[7] = (_Float16)v1.w;
#pragma unroll
        for (int ct = 0; ct < 8; ++ct) {
            int col = ct * 16 + lr;
            half8_t b = *(const half8_t*)(Wt + (size_t)col * DIM + kb);
            acc[ct] = __builtin_amdgcn_mfma_f32_16x16x32_f16(a, b, acc[ct], 0, 0, 0);
        }
    }

    int rowbase = rb + kgrp * 4;
    float dv[4];
    bool ok[4];
#pragma unroll
    for (int r = 0; r < 4; ++r) {
        int row = rowbase + r;
        ok[r] = row < NNODES;
        dv[r] = ok[r] ? dinv[row] : 0.f;
    }
#pragma unroll
    for (int ct = 0; ct < 8; ++ct) {
#pragma unroll
        for (int r = 0; r < 4; ++r) {
            if (ok[r])
                yf8[(size_t)(rowbase + r) * DIM + ct * 16 + lr] = f32_to_fp8(acc[ct][r] * dv[r]);
        }
    }
}

// Fused gather + ReLU + mean-pool partial sums (16 nodes/block, exact grid).
__global__ __launch_bounds__(256) void k_gpool(const int* __restrict__ row_ptr, const int* __restrict__ adj,
                                               const uint2* __restrict__ Y, const float* __restrict__ dinv,
                                               const float* __restrict__ bias, const int* __restrict__ batch,
                                               float* __restrict__ sums) {
    __shared__ float red[16][132];  // +4 pad
    __shared__ int gid[16];
    int tid = threadIdx.x;
    int sl = tid >> 4;   // node slot
    int l = tid & 15;    // 8B chunk (dims 8l..8l+7)
    int n = blockIdx.x * 16 + sl;

    int s = row_ptr[n], e = row_ptr[n + 1];
    float acc[8];
#pragma unroll
    for (int q = 0; q < 8; ++q) acc[q] = 0.f;
    {
        uint2 v = Y[(size_t)n * 16 + l];  // self-loop term
        fp8x4_acc(v.x, acc);
        fp8x4_acc(v.y, acc + 4);
    }
    int i = s;
    for (; i + 3 < e; i += 4) {
        int r0 = adj[i], r1 = adj[i + 1], r2 = adj[i + 2], r3 = adj[i + 3];
        uint2 a0 = Y[(size_t)r0 * 16 + l];
        uint2 a1 = Y[(size_t)r1 * 16 + l];
        uint2 a2 = Y[(size_t)r2 * 16 + l];
        uint2 a3 = Y[(size_t)r3 * 16 + l];
        fp8x4_acc(a0.x, acc); fp8x4_acc(a0.y, acc + 4);
        fp8x4_acc(a1.x, acc); fp8x4_acc(a1.y, acc + 4);
        fp8x4_acc(a2.x, acc); fp8x4_acc(a2.y, acc + 4);
        fp8x4_acc(a3.x, acc); fp8x4_acc(a3.y, acc + 4);
    }
    for (; i < e; ++i) {
        uint2 a0 = Y[(size_t)adj[i] * 16 + l];
        fp8x4_acc(a0.x, acc); fp8x4_acc(a0.y, acc + 4);
    }

    float dv = dinv[n];
#pragma unroll
    for (int q = 0; q < 8; ++q) {
        float v = dv * acc[q] + bias[l * 8 + q];
        red[sl][l * 8 + q] = fmaxf(v, 0.f);
    }
    if (l == 0) gid[sl] = batch[n];
    __syncthreads();

    if (tid < DIM) {
        int d = tid;
        float a = 0.f;
        int g = gid[0];
        for (int s2 = 0; s2 < 16; ++s2) {
            int gs = gid[s2];
            if (gs != g) {
                if (a != 0.f) atomicAdd(&sums[g * DIM + d], a);
                a = 0.f; g = gs;
            }
            a += red[s2][d];
        }
        if (a != 0.f) atomicAdd(&sums[g * DIM + d], a);
    }
}

// xg[t][j] = b_ih[j] + b_hh[j] + pooled[t] . w_ih[j]
__global__ __launch_bounds__(512) void k_xgate(const float* __restrict__ sums, const int* __restrict__ start,
                                               const float* __restrict__ w_ih, const float* __restrict__ b_ih,
                                               const float* __restrict__ b_hh, float* __restrict__ xg) {
    __shared__ float4 p4[DIM / 4];
    int t = blockIdx.x, j = threadIdx.x;
    if (j < DIM) {
        int c = start[t + 1] - start[t];
        float inv = 1.0f / fmaxf((float)c, 1.0f);
        ((float*)p4)[j] = sums[t * DIM + j] * inv;
    }
    __syncthreads();
    const float4* w4 = (const float4*)(w_ih + (size_t)j * DIM);
    float acc = b_ih[j] + b_hh[j];
#pragma unroll
    for (int kk = 0; kk < 32; ++kk) {
        float4 w = w4[kk];
        float4 p = p4[kk];
        acc += w.x * p.x + w.y * p.y + w.z * p.z + w.w * p.w;
    }
    xg[t * GATE + j] = acc;
}

// Sequential LSTM + FC via MFMA. 8 waves x 4 col-tiles; per-wave weights =
// 16 B-frags (64 VGPRs, persistent in registers -- only 16 KB/wave, fits).
// A = h in row 0 only (lanes lane&15==0 hold it); C row0 init = xg.
// Per step: 16 MFMA + ~5 LDS instrs per wave, vs R12's 32 LDS instr/thread
// (2210 cy/step LDS-issue-bound). Fragment mapping identical to k_gemmm
// (absmax-verified in R9).
__global__ __launch_bounds__(512) void k_lstmm(const float* __restrict__ xg, const __half* __restrict__ whh16,
                                               const float* __restrict__ Wfc, const float* __restrict__ bfc,
                                               float* __restrict__ out) {
    __shared__ __half h2h[DIM];
    __shared__ float gates[GATE];
    __shared__ __half hsh[NG * DIM];  // 16 KB
    int tid = threadIdx.x;
    int wid = tid >> 6, lane = tid & 63;
    int lr = lane & 15, kg = lane >> 4;
    int colbase = wid * 64;

    // persistent B-frags: col = colbase + ct*16 + lr, k = ks*32 + kg*8 .. +8
    half8_t bf[4][4];
#pragma unroll
    for (int ct = 0; ct < 4; ++ct)
#pragma unroll
        for (int ks = 0; ks < 4; ++ks)
            bf[ct][ks] = *(const half8_t*)(whh16 + (size_t)(colbase + ct * 16 + lr) * DIM + ks * 32 + kg * 8);

    if (tid < DIM) h2h[tid] = __float2half(0.f);
    float c = 0.f;
    float xc[4], xn[4];
#pragma unroll
    for (int ct = 0; ct < 4; ++ct) xc[ct] = xg[colbase + ct * 16 + lr];
    __syncthreads();

    for (int t = 0; t < NG; ++t) {
        // A-frags: row 0 = h, rows 1-15 zero (lanes with lr!=0 carry zeros)
        half8_t a[4];
#pragma unroll
        for (int ks = 0; ks < 4; ++ks) {
            half8_t av = {};
            if (lr == 0) av = *(const half8_t*)(h2h + ks * 32 + kg * 8);
            a[ks] = av;
        }
        f32x4 acc[4];
#pragma unroll
        for (int ct = 0; ct < 4; ++ct) {
            f32x4 z = (f32x4){0.f, 0.f, 0.f, 0.f};
            if (lane < 16) z[0] = xc[ct];  // C row 0 = xg pre-activation
            acc[ct] = z;
#pragma unroll
            for (int ks = 0; ks < 4; ++ks)
                acc[ct] = __builtin_amdgcn_mfma_f32_16x16x32_f16(a[ks], bf[ct][ks], acc[ct], 0, 0, 0);
        }
        int tn = (t + 1 < NG) ? t + 1 : t;
#pragma unroll
        for (int ct = 0; ct < 4; ++ct) xn[ct] = xg[tn * GATE + colbase + ct * 16 + lr];
        if (lane < 16) {
#pragma unroll
            for (int ct = 0; ct < 4; ++ct) gates[colbase + ct * 16 + lane] = acc[ct][0];
        }
        __syncthreads();
        if (tid < DIM) {
            float gi = gates[tid], gf = gates[DIM + tid], gg = gates[2 * DIM + tid], go = gates[3 * DIM + tid];
            c = sigf(gf) * c + sigf(gi) * tanhfast(gg);
            float hn = sigf(go) * tanhfast(c);
            h2h[tid] = __float2half(hn);
            hsh[t * DIM + tid] = __float2half(hn);
        }
#pragma unroll
        for (int ct = 0; ct < 4; ++ct) xc[ct] = xn[ct];
        __syncthreads();
    }

    // FC: out[t][cls] = b_fc[cls] + hs[t] . W_fc[cls]
    for (int o = tid; o < NG * 10; o += 512) {
        int t = o / 10, cls = o - t * 10;
        const __half2* hv = (const __half2*)(hsh + t * DIM);
        float acc = bfc[cls];
#pragma unroll
        for (int kk = 0; kk < 64; ++kk) {
            float2 hf = __half22float2(hv[kk]);
            acc += hf.x * Wfc[cls * DIM + 2 * kk] + hf.y * Wfc[cls * DIM + 2 * kk + 1];
        }
        out[o] = acc;
    }
}

extern "C" void kernel_launch(void* const* d_in, const int* in_sizes, int n_in,
                              void* d_out, int out_size, void* d_ws, size_t ws_size,
                              hipStream_t stream) {
    const float* x     = (const float*)d_in[0];
    const int*   ei    = (const int*)d_in[1];
    const int*   batch = (const int*)d_in[2];
    const float* W_gcn = (const float*)d_in[3];
    const float* b_gcn = (const float*)d_in[4];
    const float* w_ih  = (const float*)d_in[5];
    const float* w_hh  = (const float*)d_in[6];
    const float* b_ih  = (const float*)d_in[7];
    const float* b_hh  = (const float*)d_in[8];
    const float* W_fc  = (const float*)d_in[9];
    const float* b_fc  = (const float*)d_in[10];
    float* out = (float*)d_out;

    char* ws = (char*)d_ws;
    unsigned char* yf8 = (unsigned char*)ws;                       // 12.8 MB
    unsigned* pre8 = (unsigned*)(ws + (size_t)NNODES * DIM);       // 12.8 MB (chunk prefixes)
    __half* wt16  = (__half*)(ws + (size_t)NNODES * DIM * 2);      // 32 KB
    unsigned* partial = (unsigned*)(ws + (size_t)NNODES * DIM * 2 + (1 << 16));  // 12.8 MB
    float*  dinv  = (float*)(ws + (size_t)NNODES * DIM * 4);       // 400 KB
    float*  sums  = dinv + 100096;
    float*  xg    = sums + NG * DIM;
    int*    deg   = (int*)(xg + NG * GATE);
    int*    row_ptr = deg + 100096;
    int*    cursor  = row_ptr + 100096;
    int*    adj     = cursor + 100096;      // 6.4 MB
    int*    start   = adj + NEDGES;
    int*    bsum    = start + 128;
    __half* whh16   = (__half*)(bsum + 128);  // 128 KB fp16 LSTM weights (row-major)

    hipMemsetAsync(sums, 0, NG * DIM * sizeof(float), stream);

    bool hist_ok = hipFuncSetAttribute((const void*)k_deghist,
                                       hipFuncAttributeMaxDynamicSharedMemorySize,
                                       HSMEM) == hipSuccess;
    if (hist_ok) {
        k_deghist<<<HG, 1024, HSMEM, stream>>>(ei, partial);
        k_degred2<<<(NNODES / 4 + 255) / 256, 256, 0, stream>>>(partial, pre8, deg, dinv);
    } else {
        hipMemsetAsync(deg, 0, NNODES * sizeof(int), stream);
        k_deg<<<(NEDGES + 255) / 256, 256, 0, stream>>>(ei, deg);
        k_dinv<<<(NNODES + 255) / 256, 256, 0, stream>>>(deg, dinv);
    }
    k_scan1<<<SCAN_NB, 1024, 0, stream>>>(deg, row_ptr, bsum);
    k_scan2<<<1, 128, 0, stream>>>(bsum, row_ptr, batch, start);
    k_scan3<<<SCAN_NB, 1024, 0, stream>>>(row_ptr, bsum, cursor);
    if (hist_ok) {
        for (int p = 0; p < FILL_NPASS; ++p)
            k_fill2<<<HG, 1024, 0, stream>>>(ei, row_ptr, pre8, adj, p * BUCKET);
    } else {
        for (int p = 0; p < FILL_NPASS; ++p)
            k_fillb<<<(NEDGES + 255) / 256, 256, 0, stream>>>(ei, cursor, adj, p * BUCKET);
    }
    k_wprep<<<(GATE * DIM + DIM * DIM + 255) / 256, 256, 0, stream>>>(W_gcn, w_hh, wt16, whh16);
    k_gemmm<<<(NNODES + 63) / 64, 256, 0, stream>>>(x, wt16, dinv, yf8);
    k_gpool<<<NNODES / 16, 256, 0, stream>>>(row_ptr, adj, (const uint2*)yf8, dinv, b_gcn, batch, sums);
    k_xgate<<<NG, 512, 0, stream>>>(sums, start, w_ih, b_ih, b_hh, xg);
    k_lstmm<<<1, 512, 0, stream>>>(xg, whh16, W_fc, b_fc, out);
}